// Round 17
// baseline (768.095 us; speedup 1.0000x reference)
//
#include <hip/hip_runtime.h>
#include <cstddef>
#include <cmath>

namespace {

constexpr int H = 4, D = 32, HID = 128;
constexpr int NA = 100000, NW = 20000, NO = 50000;
constexpr int NTOT = NA + NW + NO;
constexpr int E = 150000;
constexpr float SCALE = 0.17677669529663687f;  // 1/sqrt(32)
constexpr int LDK = 3 * HID;  // kqv row stride (384)

typedef __attribute__((ext_vector_type(8))) short short8v;
typedef __attribute__((ext_vector_type(4))) float f32x4;

__device__ __forceinline__ float gelu_exact(float x) {
  return 0.5f * x * (1.f + erff(x * 0.7071067811865475f));
}
__device__ __forceinline__ unsigned short f2bf(float f) {  // RNE
  unsigned u = __float_as_uint(f);
  return (unsigned short)((u + 0x7FFF + ((u >> 16) & 1)) >> 16);
}
__device__ __forceinline__ float bf2f(unsigned short s) {
  return __uint_as_float(((unsigned)s) << 16);
}
__device__ __forceinline__ float blo(unsigned w) {
  return __uint_as_float(w << 16);
}
__device__ __forceinline__ float bhi(unsigned w) {
  return __uint_as_float(w & 0xFFFF0000u);
}

__device__ __forceinline__ int btype(int bx, int nb0, int nb01) {
  return bx < nb0 ? 0 : (bx < nb01 ? 1 : 2);
}

// ---------------- swizzled BK=64 MFMA GEMM body ----------------
template <int KSTEPS, bool A_FP32>
__device__ __forceinline__ void gemm_body(
    const void* __restrict__ Av, int lda, const unsigned short* __restrict__ BT,
    int ldb, f32x4* acc, int M, int bm) {
  __shared__ unsigned short As[64 * 64];
  __shared__ unsigned short Bs[128 * 64];
  const int tid = threadIdx.x;
  const int wv = tid >> 6, l = tid & 63;
  for (int ks = 0; ks < KSTEPS; ks++) {
    const int kk = ks * 64;
    #pragma unroll
    for (int p = 0; p < 2; p++) {
      int idx = tid + p * 256;
      int r = idx >> 3, c = idx & 7;
      int gr = bm + r;
      unsigned short tmp[8] = {0, 0, 0, 0, 0, 0, 0, 0};
      if (gr < M) {
        if (A_FP32) {
          const float* src = (const float*)Av + (size_t)gr * lda + kk + c * 8;
          float4 f0 = *(const float4*)src;
          float4 f1 = *(const float4*)(src + 4);
          tmp[0] = f2bf(f0.x); tmp[1] = f2bf(f0.y);
          tmp[2] = f2bf(f0.z); tmp[3] = f2bf(f0.w);
          tmp[4] = f2bf(f1.x); tmp[5] = f2bf(f1.y);
          tmp[6] = f2bf(f1.z); tmp[7] = f2bf(f1.w);
        } else {
          *(uint4*)tmp = *(const uint4*)((const unsigned short*)Av +
                                         (size_t)gr * lda + kk + c * 8);
        }
      }
      *(uint4*)&As[r * 64 + ((c ^ (r & 7)) * 8)] = *(const uint4*)tmp;
    }
    #pragma unroll
    for (int p = 0; p < 4; p++) {
      int idx = tid + p * 256;
      int r = idx >> 3, c = idx & 7;
      uint4 v = *(const uint4*)(BT + (size_t)r * ldb + kk + c * 8);
      *(uint4*)&Bs[r * 64 + ((c ^ (r & 7)) * 8)] = v;
    }
    __syncthreads();
    const int arow = wv * 16 + (l & 15);
    #pragma unroll
    for (int ksub = 0; ksub < 2; ksub++) {
      int ch = ksub * 4 + (l >> 4);
      short8v af = *(const short8v*)&As[arow * 64 + ((ch ^ (arow & 7)) * 8)];
      #pragma unroll
      for (int n = 0; n < 8; n++) {
        int brow = n * 16 + (l & 15);
        short8v bf =
            *(const short8v*)&Bs[brow * 64 + ((ch ^ (brow & 7)) * 8)];
        acc[n] =
            __builtin_amdgcn_mfma_f32_16x16x32_bf16(af, bf, acc[n], 0, 0, 0);
      }
    }
    __syncthreads();
  }
}

// ---------------- weight prep: bf16 transposed copies ----------------
__global__ __launch_bounds__(256) void prep_weights(
    const float* __restrict__ W_in, const float* __restrict__ W_kqv,
    const float* __restrict__ W_o, unsigned short* __restrict__ WinT,
    unsigned short* __restrict__ Wk0T, unsigned short* __restrict__ WoT) {
  int idx = blockIdx.x * 256 + threadIdx.x;
  const int N1 = 3 * 128 * 64, N2 = 2 * 384 * 128, N3 = 6 * 128 * 128;
  if (idx < N1) {
    int t = idx / 8192, rem = idx - t * 8192;
    int n = rem >> 6, k = rem & 63;
    WinT[idx] = f2bf(W_in[(size_t)t * 64 * 128 + (size_t)k * 128 + n]);
  } else if (idx < N1 + N2) {
    int r = idx - N1;
    int lyr = r / (384 * 128), rem = r - lyr * (384 * 128);
    int n = rem >> 7, k = rem & 127;
    Wk0T[r] = f2bf(W_kqv[(size_t)lyr * 3 * 128 * 384 + (size_t)k * 384 + n]);
  } else if (idx < N1 + N2 + N3) {
    int r = idx - N1 - N2;
    int lt = r / (128 * 128), rem = r - lt * (128 * 128);
    int n = rem >> 7, k = rem & 127;
    WoT[r] = f2bf(W_o[(size_t)lt * 128 * 128 + (size_t)k * 128 + n]);
  }
}

// ---------------- weight folding (per layer) -> bf16 transposed ----------
__global__ __launch_bounds__(256) void fold_weights(
    const float* __restrict__ Wl, const float* __restrict__ bl,
    const float* __restrict__ Al, const float* __restrict__ Ml,
    unsigned short* __restrict__ WeT, float* __restrict__ be) {
  int idx = blockIdx.x * 256 + threadIdx.x;
  const int NW_ = 2 * 128 * 384;
  if (idx < NW_) {
    int tt = idx / (128 * 384);
    int rem = idx - tt * (128 * 384);
    int r = rem / 384, c = rem - r * 384;
    int slice = c >> 7, h = (c >> 5) & 3, j = c & 31;
    const float* Wsrc = Wl + (size_t)(tt + 1) * 128 * 384 + (size_t)r * 384;
    float acc = 0.f;
    if (slice == 0) {
      const float* A = Al + ((size_t)tt * H + h) * D * D;
      for (int d = 0; d < 32; d++) acc += Wsrc[h * 32 + d] * A[d * 32 + j];
    } else if (slice == 1) {
      const float* A = Al + ((size_t)(2 + tt) * H + h) * D * D;
      for (int e = 0; e < 32; e++)
        acc += Wsrc[128 + h * 32 + e] * A[j * 32 + e];
    } else {
      const float* Mm = Ml + ((size_t)tt * H + h) * D * D;
      for (int d = 0; d < 32; d++)
        acc += Wsrc[256 + h * 32 + d] * Mm[d * 32 + j];
    }
    WeT[(size_t)tt * 384 * 128 + (size_t)c * 128 + r] = f2bf(acc);
  } else if (idx < NW_ + 2 * 384) {
    int rem = idx - NW_;
    int tt = rem / 384, c = rem - tt * 384;
    int slice = c >> 7, h = (c >> 5) & 3, j = c & 31;
    const float* bsrc = bl + (size_t)(tt + 1) * 384;
    float acc = 0.f;
    if (slice == 0) {
      const float* A = Al + ((size_t)tt * H + h) * D * D;
      for (int d = 0; d < 32; d++) acc += bsrc[h * 32 + d] * A[d * 32 + j];
    } else if (slice == 1) {
      const float* A = Al + ((size_t)(2 + tt) * H + h) * D * D;
      for (int e = 0; e < 32; e++)
        acc += bsrc[128 + h * 32 + e] * A[j * 32 + e];
    } else {
      const float* Mm = Ml + ((size_t)tt * H + h) * D * D;
      for (int d = 0; d < 32; d++)
        acc += bsrc[256 + h * 32 + d] * Mm[d * 32 + j];
    }
    be[rem] = acc;
  }
}

// input proj: xs = relu(x @ W_in[t] + b_in[t])
__global__ __launch_bounds__(256) void in_fused(
    const float* __restrict__ xa, const float* __restrict__ xw,
    const float* __restrict__ xo, const unsigned short* __restrict__ WinT,
    const float* __restrict__ b_in, unsigned short* __restrict__ xs, int nb0,
    int nb01) {
  int t = btype(blockIdx.x, nb0, nb01);
  int base = t == 0 ? 0 : (t == 1 ? nb0 : nb01);
  int M = t == 0 ? NA : (t == 1 ? NW : NO);
  int off = t == 0 ? 0 : (t == 1 ? NA : NA + NW);
  const float* A = t == 0 ? xa : (t == 1 ? xw : xo);
  const int bm = (blockIdx.x - base) * 64;
  f32x4 acc[8] = {};
  gemm_body<1, true>(A, 64, WinT + (size_t)t * 128 * 64, 64, acc, M, bm);
  const int l = threadIdx.x & 63, wv = threadIdx.x >> 6;
  const float* bias = b_in + t * HID;
  unsigned short* C = xs + (size_t)off * HID;
  #pragma unroll
  for (int n = 0; n < 8; n++) {
    int col = n * 16 + (l & 15);
    float bb = bias[col];
    #pragma unroll
    for (int j = 0; j < 4; j++) {
      int row = bm + wv * 16 + (l >> 4) * 4 + j;
      if (row < M) C[(size_t)row * HID + col] = f2bf(fmaxf(acc[n][j] + bb, 0.f));
    }
  }
}

// kqv proj: t=0 raw Wk0T; t=1,2 folded WeT. 64x128 tile, y = col-tile (3).
__global__ __launch_bounds__(256) void kqv_fused(
    const unsigned short* __restrict__ xs, const unsigned short* __restrict__ Wk0Tl,
    const float* __restrict__ b0, const unsigned short* __restrict__ WeT,
    const float* __restrict__ be, unsigned short* __restrict__ kqvB, int nb0,
    int nb01) {
  int t = btype(blockIdx.x, nb0, nb01);
  int base = t == 0 ? 0 : (t == 1 ? nb0 : nb01);
  int M = t == 0 ? NA : (t == 1 ? NW : NO);
  int off = t == 0 ? 0 : (t == 1 ? NA : NA + NW);
  const unsigned short* BT =
      (t == 0 ? Wk0Tl : WeT + (size_t)(t - 1) * 384 * 128);
  const float* bias = t == 0 ? b0 : be + (size_t)(t - 1) * 384;
  const int bm = (blockIdx.x - base) * 64;
  const int bn = blockIdx.y * 128;
  f32x4 acc[8] = {};
  gemm_body<2, false>(xs + (size_t)off * HID, HID, BT + (size_t)bn * 128, 128,
                      acc, M, bm);
  const int l = threadIdx.x & 63, wv = threadIdx.x >> 6;
  unsigned short* C = kqvB + (size_t)off * LDK;
  #pragma unroll
  for (int n = 0; n < 8; n++) {
    int col = bn + n * 16 + (l & 15);
    float bb = bias[col];
    #pragma unroll
    for (int j = 0; j < 4; j++) {
      int row = bm + wv * 16 + (l >> 4) * 4 + j;
      if (row < M) C[(size_t)row * LDK + col] = f2bf(acc[n][j] + bb);
    }
  }
}

// fused: xs = relu(LN( g*(agg_gelu @ W_o + b_o) + (1-g)*xs ))
__global__ __launch_bounds__(256) void wo_ln_fused(
    const unsigned short* __restrict__ kqvB, const unsigned short* __restrict__ WoTl,
    const float* __restrict__ bl, unsigned short* __restrict__ xs,
    const float* __restrict__ skipl, const float* __restrict__ gll,
    const float* __restrict__ bll, int nb0, int nb01) {
  int t = btype(blockIdx.x, nb0, nb01);
  int base = t == 0 ? 0 : (t == 1 ? nb0 : nb01);
  int M = t == 0 ? NA : (t == 1 ? NW : NO);
  int off = t == 0 ? 0 : (t == 1 ? NA : NA + NW);
  const int bm = (blockIdx.x - base) * 64;
  f32x4 acc[8] = {};
  gemm_body<2, false>(kqvB + (size_t)off * LDK + HID, LDK,
                      WoTl + (size_t)t * 128 * 128, 128, acc, M, bm);
  const int l = threadIdx.x & 63, wv = threadIdx.x >> 6;
  const float* bias = bl + t * HID;
  const float* gln = gll + t * HID;
  const float* bln = bll + t * HID;
  unsigned short* xsT = xs + (size_t)off * HID;
  const float g = 1.f / (1.f + expf(-skipl[t]));
  float bb[8], gl8[8], bl8[8];
  #pragma unroll
  for (int n = 0; n < 8; n++) {
    int col = n * 16 + (l & 15);
    bb[n] = bias[col];
    gl8[n] = gln[col];
    bl8[n] = bln[col];
  }
  #pragma unroll
  for (int j = 0; j < 4; j++) {
    int row = bm + wv * 16 + (l >> 4) * 4 + j;
    bool ok = row < M;
    float vv[8], sum = 0.f, sq = 0.f;
    #pragma unroll
    for (int n = 0; n < 8; n++) {
      int col = n * 16 + (l & 15);
      float xo = ok ? bf2f(xsT[(size_t)row * HID + col]) : 0.f;
      float val = g * (acc[n][j] + bb[n]) + (1.f - g) * xo;
      vv[n] = val;
      sum += val;
      sq += val * val;
    }
    #pragma unroll
    for (int m = 1; m < 16; m <<= 1) {
      sum += __shfl_xor(sum, m, 64);
      sq += __shfl_xor(sq, m, 64);
    }
    float mu = sum * (1.f / 128.f);
    float var = sq * (1.f / 128.f) - mu * mu;
    float r = rsqrtf(var + 1e-5f);
    if (ok) {
      #pragma unroll
      for (int n = 0; n < 8; n++) {
        float y = fmaxf((vv[n] - mu) * r * gl8[n] + bl8[n], 0.f);
        xsT[(size_t)row * HID + n * 16 + (l & 15)] = f2bf(y);
      }
    }
  }
}

// ---------------- CSR build (deterministic, 4 ets fused) ----------------
__global__ __launch_bounds__(256) void csr_hist4(
    const int* __restrict__ d0, const int* __restrict__ d1,
    const int* __restrict__ d2, const int* __restrict__ d3,
    int* __restrict__ cnt) {
  int t = blockIdx.x * 256 + threadIdx.x;
  if (t >= 4 * E) return;
  int et = t / E, e = t - et * E;
  const int* dp = et == 0 ? d0 : et == 1 ? d1 : et == 2 ? d2 : d3;
  int base = et == 0 ? 0 : et == 1 ? NA : et == 2 ? 2 * NA : 2 * NA + NW;
  atomicAdd(&cnt[base + dp[e]], 1);
}

// fused per-256-block scan over all 4 et regions (grid partitioned by et)
__global__ __launch_bounds__(256) void scan_block_all(
    const int* __restrict__ cnt, int* __restrict__ rpAll,
    int* __restrict__ bsum) {
  const int nbA = (NA + 255) / 256, nbW = (NW + 255) / 256,
            nbO = (NO + 255) / 256;
  int bx = blockIdx.x;
  int et, bbase, cbase, rpo, n;
  if (bx < nbA) { et = 0; bbase = 0; cbase = 0; rpo = 0; n = NA; }
  else if (bx < 2 * nbA) { et = 1; bbase = nbA; cbase = NA; rpo = NA + 1; n = NA; }
  else if (bx < 2 * nbA + nbW) {
    et = 2; bbase = 2 * nbA; cbase = 2 * NA; rpo = 2 * (NA + 1); n = NW;
  } else {
    et = 3; bbase = 2 * nbA + nbW; cbase = 2 * NA + NW;
    rpo = 2 * (NA + 1) + (NW + 1); n = NO;
  }
  int lb = bx - bbase;
  __shared__ int tmp[256];
  int i = lb * 256 + threadIdx.x;
  int v = (i < n) ? cnt[cbase + i] : 0;
  tmp[threadIdx.x] = v;
  __syncthreads();
  int acc = v;
  for (int off = 1; off < 256; off <<= 1) {
    int other = (threadIdx.x >= off) ? tmp[threadIdx.x - off] : 0;
    __syncthreads();
    acc += other;
    tmp[threadIdx.x] = acc;
    __syncthreads();
  }
  if (i < n) rpAll[rpo + i] = acc - v;
  if (threadIdx.x == 255) bsum[et * 512 + lb] = acc;
}

// fused bsum scans: 4 blocks, one per et
__global__ __launch_bounds__(256) void scan_bsums_all(int* __restrict__ bsum) {
  int et = blockIdx.x;
  int nb = et < 2 ? (NA + 255) / 256 : (et == 2 ? (NW + 255) / 256
                                                : (NO + 255) / 256);
  int* bs = bsum + et * 512;
  __shared__ int tmp[256];
  __shared__ int carry;
  if (threadIdx.x == 0) carry = 0;
  __syncthreads();
  for (int start = 0; start < nb; start += 256) {
    int i = start + threadIdx.x;
    int v = (i < nb) ? bs[i] : 0;
    tmp[threadIdx.x] = v;
    __syncthreads();
    int acc = v;
    for (int off = 1; off < 256; off <<= 1) {
      int other = (threadIdx.x >= off) ? tmp[threadIdx.x - off] : 0;
      __syncthreads();
      acc += other;
      tmp[threadIdx.x] = acc;
      __syncthreads();
    }
    int c = carry;
    if (i < nb) bs[i] = c + acc - v;
    __syncthreads();
    if (threadIdx.x == 255) carry = c + acc;
    __syncthreads();
  }
}

__device__ __forceinline__ void et_of_node(int i, int& et, int& base, int& nd,
                                           int& rpo) {
  if (i < NA) { et = 0; base = 0; nd = NA; rpo = 0; }
  else if (i < 2 * NA) { et = 1; base = NA; nd = NA; rpo = NA + 1; }
  else if (i < 2 * NA + NW) { et = 2; base = 2 * NA; nd = NW; rpo = 2 * (NA + 1); }
  else { et = 3; base = 2 * NA + NW; nd = NO; rpo = 2 * (NA + 1) + NW + 1; }
}

__global__ __launch_bounds__(256) void csr_finalize4(
    int* __restrict__ rpAll, const int* __restrict__ bsum,
    int* __restrict__ cursor) {
  int i = blockIdx.x * 256 + threadIdx.x;
  if (i >= 2 * NA + NW + NO) return;
  int et, base, nd, rpo;
  et_of_node(i, et, base, nd, rpo);
  int local = i - base;
  int v = rpAll[rpo + local] + bsum[et * 512 + (local >> 8)];
  rpAll[rpo + local] = v;
  cursor[base + local] = v;
  if (local == 0) rpAll[rpo + nd] = E;
}

__global__ __launch_bounds__(256) void csr_scatter4(
    const int* __restrict__ d0, const int* __restrict__ d1,
    const int* __restrict__ d2, const int* __restrict__ d3,
    int* __restrict__ cursor, int* __restrict__ ceAll) {
  int t = blockIdx.x * 256 + threadIdx.x;
  if (t >= 4 * E) return;
  int et = t / E, e = t - et * E;
  const int* dp = et == 0 ? d0 : et == 1 ? d1 : et == 2 ? d2 : d3;
  int base = et == 0 ? 0 : et == 1 ? NA : et == 2 ? 2 * NA : 2 * NA + NW;
  int slot = atomicAdd(&cursor[base + dp[e]], 1);
  ceAll[(size_t)et * E + slot] = e;
}

__global__ __launch_bounds__(256) void csr_sort4(const int* __restrict__ rpAll,
                                                 int* __restrict__ ceAll) {
  int i = blockIdx.x * 256 + threadIdx.x;
  if (i >= 2 * NA + NW + NO) return;
  int et, base, nd, rpo;
  et_of_node(i, et, base, nd, rpo);
  int local = i - base;
  int b = rpAll[rpo + local], e = rpAll[rpo + local + 1];
  int* ce = ceAll + (size_t)et * E;
  for (int k = b + 1; k < e; k++) {
    int key = ce[k];
    int j = k - 1;
    while (j >= b && ce[j] > key) { ce[j + 1] = ce[j]; j--; }
    ce[j + 1] = key;
  }
}

// slot-ordered GLOBAL src node ids
__global__ __launch_bounds__(256) void build_sd(
    const int* __restrict__ ce, const int* __restrict__ s0,
    const int* __restrict__ s1, const int* __restrict__ s2,
    const int* __restrict__ s3, int* __restrict__ srcOf) {
  int t = blockIdx.x * 256 + threadIdx.x;
  if (t >= 4 * E) return;
  int et = t / E;
  int e = ce[t];
  const int* sp = et == 0 ? s0 : et == 1 ? s1 : et == 2 ? s2 : s3;
  int sOff = et == 0 ? NA : et == 1 ? NA + NW : 0;
  srcOf[t] = sOff + sp[e];
}

// ---------------- fused attention (chunk-8 batched online softmax) --------
// one 64-lane wave per dst; lane = dim-pair; quarter q = lane>>4 = head.
// per chunk of 8 edges: burst-load 16 rows, 8 interleaved shfl dot chains,
// one rescale per chunk.
__global__ __launch_bounds__(256) void attn_fused(
    const unsigned short* __restrict__ kqv, const int* __restrict__ rpAll,
    const int* __restrict__ srcOf, const float* __restrict__ Pl,
    const float* __restrict__ Ml, unsigned short* __restrict__ out) {
  int dl = (blockIdx.x * 256 + threadIdx.x) >> 6;
  int lane = threadIdx.x & 63;
  if (dl >= NTOT) return;
  int q = lane >> 4, p = lane & 15;
  int b0, e0, b1 = 0, e1 = 0, et23 = -1;
  const int* so0;
  const int* so1 = srcOf;
  float ps0, ps1 = 0.f;
  if (dl < NA) {
    b0 = rpAll[dl]; e0 = rpAll[dl + 1];
    b1 = rpAll[(NA + 1) + dl]; e1 = rpAll[(NA + 1) + dl + 1];
    so0 = srcOf; so1 = srcOf + E;
    ps0 = Pl[q] * SCALE; ps1 = Pl[H + q] * SCALE;
  } else if (dl < NA + NW) {
    int x = dl - NA;
    b0 = rpAll[2 * (NA + 1) + x]; e0 = rpAll[2 * (NA + 1) + x + 1];
    so0 = srcOf + 2 * (size_t)E;
    ps0 = Pl[2 * H + q] * SCALE;
    et23 = 2;
  } else {
    int x = dl - NA - NW;
    b0 = rpAll[2 * (NA + 1) + (NW + 1) + x];
    e0 = rpAll[2 * (NA + 1) + (NW + 1) + x + 1];
    so0 = srcOf + 3 * (size_t)E;
    ps0 = Pl[3 * H + q] * SCALE;
    et23 = 3;
  }
  const int n0 = e0 - b0;
  const int n01 = n0 + (e1 - b1);
  // q-row (one coalesced 256B load, stays in regs)
  unsigned qv = *(const unsigned*)(kqv + (size_t)dl * LDK + HID + lane * 2);
  float qx = blo(qv), qy = bhi(qv);
  const int lo2 = lane * 2;

  float m = -INFINITY, den = 0.f, ax = 0.f, ay = 0.f;
  for (int c0 = 0; c0 < n01; c0 += 8) {
    int nn = n01 - c0;
    if (nn > 8) nn = 8;
    unsigned kk[8], vv[8];
    float s[8];
    // burst load: up to 16 independent gathers in flight
    #pragma unroll
    for (int t = 0; t < 8; t++) {
      kk[t] = 0;
      vv[t] = 0;
      if (t < nn) {
        int g = c0 + t;
        int src = (g < n0) ? so0[b0 + g] : so1[b1 + (g - n0)];
        const unsigned short* r = kqv + (size_t)src * LDK;
        kk[t] = *(const unsigned*)(r + lo2);
        vv[t] = *(const unsigned*)(r + 2 * HID + lo2);
      }
    }
    // 8 interleaved dot chains
    #pragma unroll
    for (int t = 0; t < 8; t++) s[t] = qx * blo(kk[t]) + qy * bhi(kk[t]);
    #pragma unroll
    for (int st = 1; st <= 8; st <<= 1) {
      #pragma unroll
      for (int t = 0; t < 8; t++) s[t] += __shfl_xor(s[t], st, 64);
    }
    #pragma unroll
    for (int t = 0; t < 8; t++) {
      int g = c0 + t;
      s[t] = (t < nn) ? s[t] * ((g < n0) ? ps0 : ps1) : -INFINITY;
    }
    // chunk max, one rescale, 8 exps
    float cm = s[0];
    #pragma unroll
    for (int t = 1; t < 8; t++) cm = fmaxf(cm, s[t]);
    float nm = fmaxf(m, cm);
    float cc = __expf(m - nm);  // 0 on first chunk (m=-inf)
    den *= cc;
    ax *= cc;
    ay *= cc;
    #pragma unroll
    for (int t = 0; t < 8; t++) {
      float w = __expf(s[t] - nm);  // 0 for invalid slots
      den += w;
      ax += w * blo(vv[t]);
      ay += w * bhi(vv[t]);
    }
    m = nm;
  }
  float inv = 1.f / (den + 1e-16f);
  ax *= inv;
  ay *= inv;
  // W/O dst: M transform (raw-v aggregated; apply per-dst once)
  if (et23 >= 0) {
    const float* Mm = Ml + ((size_t)et23 * H + q) * D * D;
    int base = lane & 48;
    float o0 = 0.f, o1 = 0.f;
    #pragma unroll
    for (int j = 0; j < 16; j++) {
      float s0 = __shfl(ax, base + j, 64);
      float s1 = __shfl(ay, base + j, 64);
      float2 m0 = *(const float2*)&Mm[(2 * j) * 32 + 2 * p];
      float2 m1 = *(const float2*)&Mm[(2 * j + 1) * 32 + 2 * p];
      o0 += s0 * m0.x + s1 * m1.x;
      o1 += s0 * m0.y + s1 * m1.y;
    }
    ax = o0;
    ay = o1;
  }
  unsigned ov = (unsigned)f2bf(gelu_exact(ax)) |
                ((unsigned)f2bf(gelu_exact(ay)) << 16);
  *(unsigned*)(out + (size_t)dl * LDK + HID + lane * 2) = ov;
}

__global__ __launch_bounds__(256) void head_kernel(
    const unsigned short* __restrict__ xs0, const float* __restrict__ w_head,
    const float* __restrict__ b_head, const float* __restrict__ basep,
    float* __restrict__ out, int Nrows) {
  int wid = (blockIdx.x * 256 + threadIdx.x) >> 6;
  int lane = threadIdx.x & 63;
  if (wid >= Nrows) return;
  size_t base = (size_t)wid * HID;
  float d = bf2f(xs0[base + lane]) * w_head[lane] +
            bf2f(xs0[base + 64 + lane]) * w_head[64 + lane];
  #pragma unroll
  for (int m = 1; m < 64; m <<= 1) d += __shfl_xor(d, m, 64);
  if (lane == 0) out[wid] = basep[0] + b_head[0] + d;
}

}  // namespace

extern "C" void kernel_launch(void* const* d_in, const int* in_sizes, int n_in,
                              void* d_out, int out_size, void* d_ws,
                              size_t ws_size, hipStream_t stream) {
  const float* x_a = (const float*)d_in[0];
  const float* x_w = (const float*)d_in[1];
  const float* x_o = (const float*)d_in[2];
  const float* W_in = (const float*)d_in[3];
  const float* b_in = (const float*)d_in[4];
  const float* W_kqv = (const float*)d_in[5];
  const float* b_kqv = (const float*)d_in[6];
  const float* a_rel = (const float*)d_in[7];
  const float* m_rel = (const float*)d_in[8];
  const float* p_rel = (const float*)d_in[9];
  const float* skip_p = (const float*)d_in[10];
  const float* W_o = (const float*)d_in[11];
  const float* b_o = (const float*)d_in[12];
  const float* ln_g = (const float*)d_in[13];
  const float* ln_b = (const float*)d_in[14];
  const float* w_head = (const float*)d_in[15];
  const float* b_head = (const float*)d_in[16];
  const float* basep = (const float*)d_in[17];
  const int* srcs[4] = {(const int*)d_in[18], (const int*)d_in[20],
                        (const int*)d_in[22], (const int*)d_in[24]};
  const int* dsts[4] = {(const int*)d_in[19], (const int*)d_in[21],
                        (const int*)d_in[23], (const int*)d_in[25]};

  // ---- workspace layout (~183 MB) ----
  const size_t SZ_XS = (size_t)NTOT * HID * 2;
  const size_t SZ_KQV = (size_t)NTOT * LDK * 2;
  const size_t SZ_WINT = (size_t)3 * 128 * 64 * 2;
  const size_t SZ_WK0T = (size_t)2 * 384 * 128 * 2;
  const size_t SZ_WOT = (size_t)6 * 128 * 128 * 2;
  const size_t SZ_WET = (size_t)2 * 384 * 128 * 2;
  const size_t SZ_BE = ((size_t)2 * 384 * 4 + 63) & ~63ull;
  const size_t SZ_SD = (size_t)4 * E * 4;
  const int CNT_TOT = 2 * NA + NW + NO;
  const int RP_TOT = 2 * (NA + 1) + (NW + 1) + (NO + 1);
  const size_t SZ_RP = ((size_t)RP_TOT * 4 + 63) & ~63ull;
  const size_t SZ_CE = (size_t)4 * E * 4;
  const size_t SZ_CU = ((size_t)CNT_TOT * 4 + 63) & ~63ull;
  const size_t SZ_BS = 4 * 512 * 4;
  const size_t need = SZ_XS + SZ_KQV + SZ_WINT + SZ_WK0T + SZ_WOT + SZ_WET +
                      SZ_BE + SZ_SD + SZ_RP + SZ_CE + 2 * SZ_CU + SZ_BS;
  if (ws_size < need) return;

  char* p = (char*)d_ws;
  unsigned short* xs = (unsigned short*)p;    p += SZ_XS;
  unsigned short* kqvB = (unsigned short*)p;  p += SZ_KQV;
  unsigned short* WinT = (unsigned short*)p;  p += SZ_WINT;
  unsigned short* Wk0T = (unsigned short*)p;  p += SZ_WK0T;
  unsigned short* WoT = (unsigned short*)p;   p += SZ_WOT;
  unsigned short* WeT = (unsigned short*)p;   p += SZ_WET;
  float* beB = (float*)p;                     p += SZ_BE;
  int* srcOf = (int*)p;                       p += SZ_SD;
  int* rpAll = (int*)p;                       p += SZ_RP;
  int* ceAll = (int*)p;                       p += SZ_CE;
  int* cursor = (int*)p;                      p += SZ_CU;
  int* cnt = (int*)p;                         p += SZ_CU;
  int* bsum = (int*)p;

  const int CNTT = 2 * NA + NW + NO;
  const int e4b = (4 * E + 255) / 256;
  const int nb0 = (NA + 63) / 64, nb01 = nb0 + (NW + 63) / 64;
  const int nbTot = nb01 + (NO + 63) / 64;
  const int nbA = (NA + 255) / 256, nbW = (NW + 255) / 256,
            nbO = (NO + 255) / 256;

  // ---- CSR build (once) ----
  hipMemsetAsync(cnt, 0, (size_t)CNTT * 4, stream);
  csr_hist4<<<e4b, 256, 0, stream>>>(dsts[0], dsts[1], dsts[2], dsts[3], cnt);
  scan_block_all<<<2 * nbA + nbW + nbO, 256, 0, stream>>>(cnt, rpAll, bsum);
  scan_bsums_all<<<4, 256, 0, stream>>>(bsum);
  csr_finalize4<<<(CNTT + 255) / 256, 256, 0, stream>>>(rpAll, bsum, cursor);
  csr_scatter4<<<e4b, 256, 0, stream>>>(dsts[0], dsts[1], dsts[2], dsts[3],
                                        cursor, ceAll);
  csr_sort4<<<(CNTT + 255) / 256, 256, 0, stream>>>(rpAll, ceAll);
  build_sd<<<e4b, 256, 0, stream>>>(ceAll, srcs[0], srcs[1], srcs[2], srcs[3],
                                    srcOf);

  // ---- weight prep + input projection ----
  prep_weights<<<(3 * 128 * 64 + 2 * 384 * 128 + 6 * 128 * 128 + 255) / 256,
                 256, 0, stream>>>(W_in, W_kqv, W_o, WinT, Wk0T, WoT);
  in_fused<<<nbTot, 256, 0, stream>>>(x_a, x_w, x_o, WinT, b_in, xs, nb0, nb01);

  const size_t DD = (size_t)H * D * D;
  for (int l = 0; l < 2; l++) {
    const float* Al = a_rel + (size_t)l * 4 * DD;
    const float* Ml = m_rel + (size_t)l * 4 * DD;
    const float* Pl = p_rel + (size_t)l * 4 * H;
    const float* Wl = W_kqv + (size_t)l * 3 * HID * LDK;
    const float* bl = b_kqv + (size_t)l * 3 * LDK;
    fold_weights<<<(2 * 128 * 384 + 2 * 384 + 255) / 256, 256, 0, stream>>>(
        Wl, bl, Al, Ml, WeT, beB);
    kqv_fused<<<dim3(nbTot, 3), 256, 0, stream>>>(
        xs, Wk0T + (size_t)l * 384 * 128, bl, WeT, beB, kqvB, nb0, nb01);
    attn_fused<<<(NTOT + 3) / 4, 256, 0, stream>>>(kqvB, rpAll, srcOf, Pl, Ml,
                                                   kqvB);
    wo_ln_fused<<<nbTot, 256, 0, stream>>>(
        kqvB, WoT + (size_t)l * 3 * 128 * 128, b_o + (size_t)l * 3 * HID, xs,
        skip_p + l * 3, ln_g + (size_t)l * 3 * HID, ln_b + (size_t)l * 3 * HID,
        nb0, nb01);
  }
  head_kernel<<<(NA + 3) / 4, 256, 0, stream>>>(xs, w_head, b_head, basep,
                                                (float*)d_out, NA);
}

// Round 18
// 710.698 us; speedup vs baseline: 1.0808x; 1.0808x over previous
//
#include <hip/hip_runtime.h>
#include <cstddef>
#include <cmath>

namespace {

constexpr int H = 4, D = 32, HID = 128;
constexpr int NA = 100000, NW = 20000, NO = 50000;
constexpr int NTOT = NA + NW + NO;
constexpr int E = 150000;
constexpr float SCALE = 0.17677669529663687f;  // 1/sqrt(32)
constexpr int LDK = 3 * HID;  // kqv row stride (384)

typedef __attribute__((ext_vector_type(8))) short short8v;
typedef __attribute__((ext_vector_type(4))) float f32x4;

__device__ __forceinline__ float gelu_exact(float x) {
  return 0.5f * x * (1.f + erff(x * 0.7071067811865475f));
}
__device__ __forceinline__ unsigned short f2bf(float f) {  // RNE
  unsigned u = __float_as_uint(f);
  return (unsigned short)((u + 0x7FFF + ((u >> 16) & 1)) >> 16);
}
__device__ __forceinline__ float bf2f(unsigned short s) {
  return __uint_as_float(((unsigned)s) << 16);
}
__device__ __forceinline__ float blo(unsigned w) {
  return __uint_as_float(w << 16);
}
__device__ __forceinline__ float bhi(unsigned w) {
  return __uint_as_float(w & 0xFFFF0000u);
}

__device__ __forceinline__ int btype(int bx, int nb0, int nb01) {
  return bx < nb0 ? 0 : (bx < nb01 ? 1 : 2);
}

// ---------------- swizzled BK=64 MFMA GEMM body ----------------
template <int KSTEPS, bool A_FP32>
__device__ __forceinline__ void gemm_body(
    const void* __restrict__ Av, int lda, const unsigned short* __restrict__ BT,
    int ldb, f32x4* acc, int M, int bm) {
  __shared__ unsigned short As[64 * 64];
  __shared__ unsigned short Bs[128 * 64];
  const int tid = threadIdx.x;
  const int wv = tid >> 6, l = tid & 63;
  for (int ks = 0; ks < KSTEPS; ks++) {
    const int kk = ks * 64;
    #pragma unroll
    for (int p = 0; p < 2; p++) {
      int idx = tid + p * 256;
      int r = idx >> 3, c = idx & 7;
      int gr = bm + r;
      unsigned short tmp[8] = {0, 0, 0, 0, 0, 0, 0, 0};
      if (gr < M) {
        if (A_FP32) {
          const float* src = (const float*)Av + (size_t)gr * lda + kk + c * 8;
          float4 f0 = *(const float4*)src;
          float4 f1 = *(const float4*)(src + 4);
          tmp[0] = f2bf(f0.x); tmp[1] = f2bf(f0.y);
          tmp[2] = f2bf(f0.z); tmp[3] = f2bf(f0.w);
          tmp[4] = f2bf(f1.x); tmp[5] = f2bf(f1.y);
          tmp[6] = f2bf(f1.z); tmp[7] = f2bf(f1.w);
        } else {
          *(uint4*)tmp = *(const uint4*)((const unsigned short*)Av +
                                         (size_t)gr * lda + kk + c * 8);
        }
      }
      *(uint4*)&As[r * 64 + ((c ^ (r & 7)) * 8)] = *(const uint4*)tmp;
    }
    #pragma unroll
    for (int p = 0; p < 4; p++) {
      int idx = tid + p * 256;
      int r = idx >> 3, c = idx & 7;
      uint4 v = *(const uint4*)(BT + (size_t)r * ldb + kk + c * 8);
      *(uint4*)&Bs[r * 64 + ((c ^ (r & 7)) * 8)] = v;
    }
    __syncthreads();
    const int arow = wv * 16 + (l & 15);
    #pragma unroll
    for (int ksub = 0; ksub < 2; ksub++) {
      int ch = ksub * 4 + (l >> 4);
      short8v af = *(const short8v*)&As[arow * 64 + ((ch ^ (arow & 7)) * 8)];
      #pragma unroll
      for (int n = 0; n < 8; n++) {
        int brow = n * 16 + (l & 15);
        short8v bf =
            *(const short8v*)&Bs[brow * 64 + ((ch ^ (brow & 7)) * 8)];
        acc[n] =
            __builtin_amdgcn_mfma_f32_16x16x32_bf16(af, bf, acc[n], 0, 0, 0);
      }
    }
    __syncthreads();
  }
}

// ---------------- weight prep: bf16 transposed copies ----------------
__global__ __launch_bounds__(256) void prep_weights(
    const float* __restrict__ W_in, const float* __restrict__ W_kqv,
    const float* __restrict__ W_o, unsigned short* __restrict__ WinT,
    unsigned short* __restrict__ Wk0T, unsigned short* __restrict__ WoT) {
  int idx = blockIdx.x * 256 + threadIdx.x;
  const int N1 = 3 * 128 * 64, N2 = 2 * 384 * 128, N3 = 6 * 128 * 128;
  if (idx < N1) {
    int t = idx / 8192, rem = idx - t * 8192;
    int n = rem >> 6, k = rem & 63;
    WinT[idx] = f2bf(W_in[(size_t)t * 64 * 128 + (size_t)k * 128 + n]);
  } else if (idx < N1 + N2) {
    int r = idx - N1;
    int lyr = r / (384 * 128), rem = r - lyr * (384 * 128);
    int n = rem >> 7, k = rem & 127;
    Wk0T[r] = f2bf(W_kqv[(size_t)lyr * 3 * 128 * 384 + (size_t)k * 384 + n]);
  } else if (idx < N1 + N2 + N3) {
    int r = idx - N1 - N2;
    int lt = r / (128 * 128), rem = r - lt * (128 * 128);
    int n = rem >> 7, k = rem & 127;
    WoT[r] = f2bf(W_o[(size_t)lt * 128 * 128 + (size_t)k * 128 + n]);
  }
}

// ---------------- weight folding (per layer) -> bf16 transposed ----------
__global__ __launch_bounds__(256) void fold_weights(
    const float* __restrict__ Wl, const float* __restrict__ bl,
    const float* __restrict__ Al, const float* __restrict__ Ml,
    unsigned short* __restrict__ WeT, float* __restrict__ be) {
  int idx = blockIdx.x * 256 + threadIdx.x;
  const int NW_ = 2 * 128 * 384;
  if (idx < NW_) {
    int tt = idx / (128 * 384);
    int rem = idx - tt * (128 * 384);
    int r = rem / 384, c = rem - r * 384;
    int slice = c >> 7, h = (c >> 5) & 3, j = c & 31;
    const float* Wsrc = Wl + (size_t)(tt + 1) * 128 * 384 + (size_t)r * 384;
    float acc = 0.f;
    if (slice == 0) {
      const float* A = Al + ((size_t)tt * H + h) * D * D;
      for (int d = 0; d < 32; d++) acc += Wsrc[h * 32 + d] * A[d * 32 + j];
    } else if (slice == 1) {
      const float* A = Al + ((size_t)(2 + tt) * H + h) * D * D;
      for (int e = 0; e < 32; e++)
        acc += Wsrc[128 + h * 32 + e] * A[j * 32 + e];
    } else {
      const float* Mm = Ml + ((size_t)tt * H + h) * D * D;
      for (int d = 0; d < 32; d++)
        acc += Wsrc[256 + h * 32 + d] * Mm[d * 32 + j];
    }
    WeT[(size_t)tt * 384 * 128 + (size_t)c * 128 + r] = f2bf(acc);
  } else if (idx < NW_ + 2 * 384) {
    int rem = idx - NW_;
    int tt = rem / 384, c = rem - tt * 384;
    int slice = c >> 7, h = (c >> 5) & 3, j = c & 31;
    const float* bsrc = bl + (size_t)(tt + 1) * 384;
    float acc = 0.f;
    if (slice == 0) {
      const float* A = Al + ((size_t)tt * H + h) * D * D;
      for (int d = 0; d < 32; d++) acc += bsrc[h * 32 + d] * A[d * 32 + j];
    } else if (slice == 1) {
      const float* A = Al + ((size_t)(2 + tt) * H + h) * D * D;
      for (int e = 0; e < 32; e++)
        acc += bsrc[128 + h * 32 + e] * A[j * 32 + e];
    } else {
      const float* Mm = Ml + ((size_t)tt * H + h) * D * D;
      for (int d = 0; d < 32; d++)
        acc += bsrc[256 + h * 32 + d] * Mm[d * 32 + j];
    }
    be[rem] = acc;
  }
}

// input proj: xs = relu(x @ W_in[t] + b_in[t])
__global__ __launch_bounds__(256) void in_fused(
    const float* __restrict__ xa, const float* __restrict__ xw,
    const float* __restrict__ xo, const unsigned short* __restrict__ WinT,
    const float* __restrict__ b_in, unsigned short* __restrict__ xs, int nb0,
    int nb01) {
  int t = btype(blockIdx.x, nb0, nb01);
  int base = t == 0 ? 0 : (t == 1 ? nb0 : nb01);
  int M = t == 0 ? NA : (t == 1 ? NW : NO);
  int off = t == 0 ? 0 : (t == 1 ? NA : NA + NW);
  const float* A = t == 0 ? xa : (t == 1 ? xw : xo);
  const int bm = (blockIdx.x - base) * 64;
  f32x4 acc[8] = {};
  gemm_body<1, true>(A, 64, WinT + (size_t)t * 128 * 64, 64, acc, M, bm);
  const int l = threadIdx.x & 63, wv = threadIdx.x >> 6;
  const float* bias = b_in + t * HID;
  unsigned short* C = xs + (size_t)off * HID;
  #pragma unroll
  for (int n = 0; n < 8; n++) {
    int col = n * 16 + (l & 15);
    float bb = bias[col];
    #pragma unroll
    for (int j = 0; j < 4; j++) {
      int row = bm + wv * 16 + (l >> 4) * 4 + j;
      if (row < M) C[(size_t)row * HID + col] = f2bf(fmaxf(acc[n][j] + bb, 0.f));
    }
  }
}

// kqv proj: t=0 raw Wk0T; t=1,2 folded WeT. 64x128 tile, y = col-tile (3).
__global__ __launch_bounds__(256) void kqv_fused(
    const unsigned short* __restrict__ xs, const unsigned short* __restrict__ Wk0Tl,
    const float* __restrict__ b0, const unsigned short* __restrict__ WeT,
    const float* __restrict__ be, unsigned short* __restrict__ kqvB, int nb0,
    int nb01) {
  int t = btype(blockIdx.x, nb0, nb01);
  int base = t == 0 ? 0 : (t == 1 ? nb0 : nb01);
  int M = t == 0 ? NA : (t == 1 ? NW : NO);
  int off = t == 0 ? 0 : (t == 1 ? NA : NA + NW);
  const unsigned short* BT =
      (t == 0 ? Wk0Tl : WeT + (size_t)(t - 1) * 384 * 128);
  const float* bias = t == 0 ? b0 : be + (size_t)(t - 1) * 384;
  const int bm = (blockIdx.x - base) * 64;
  const int bn = blockIdx.y * 128;
  f32x4 acc[8] = {};
  gemm_body<2, false>(xs + (size_t)off * HID, HID, BT + (size_t)bn * 128, 128,
                      acc, M, bm);
  const int l = threadIdx.x & 63, wv = threadIdx.x >> 6;
  unsigned short* C = kqvB + (size_t)off * LDK;
  #pragma unroll
  for (int n = 0; n < 8; n++) {
    int col = bn + n * 16 + (l & 15);
    float bb = bias[col];
    #pragma unroll
    for (int j = 0; j < 4; j++) {
      int row = bm + wv * 16 + (l >> 4) * 4 + j;
      if (row < M) C[(size_t)row * LDK + col] = f2bf(acc[n][j] + bb);
    }
  }
}

// fused: xs = relu(LN( g*(agg_gelu @ W_o + b_o) + (1-g)*xs ))
__global__ __launch_bounds__(256) void wo_ln_fused(
    const unsigned short* __restrict__ kqvB, const unsigned short* __restrict__ WoTl,
    const float* __restrict__ bl, unsigned short* __restrict__ xs,
    const float* __restrict__ skipl, const float* __restrict__ gll,
    const float* __restrict__ bll, int nb0, int nb01) {
  int t = btype(blockIdx.x, nb0, nb01);
  int base = t == 0 ? 0 : (t == 1 ? nb0 : nb01);
  int M = t == 0 ? NA : (t == 1 ? NW : NO);
  int off = t == 0 ? 0 : (t == 1 ? NA : NA + NW);
  const int bm = (blockIdx.x - base) * 64;
  f32x4 acc[8] = {};
  gemm_body<2, false>(kqvB + (size_t)off * LDK + HID, LDK,
                      WoTl + (size_t)t * 128 * 128, 128, acc, M, bm);
  const int l = threadIdx.x & 63, wv = threadIdx.x >> 6;
  const float* bias = bl + t * HID;
  const float* gln = gll + t * HID;
  const float* bln = bll + t * HID;
  unsigned short* xsT = xs + (size_t)off * HID;
  const float g = 1.f / (1.f + expf(-skipl[t]));
  float bb[8], gl8[8], bl8[8];
  #pragma unroll
  for (int n = 0; n < 8; n++) {
    int col = n * 16 + (l & 15);
    bb[n] = bias[col];
    gl8[n] = gln[col];
    bl8[n] = bln[col];
  }
  #pragma unroll
  for (int j = 0; j < 4; j++) {
    int row = bm + wv * 16 + (l >> 4) * 4 + j;
    bool ok = row < M;
    float vv[8], sum = 0.f, sq = 0.f;
    #pragma unroll
    for (int n = 0; n < 8; n++) {
      int col = n * 16 + (l & 15);
      float xo = ok ? bf2f(xsT[(size_t)row * HID + col]) : 0.f;
      float val = g * (acc[n][j] + bb[n]) + (1.f - g) * xo;
      vv[n] = val;
      sum += val;
      sq += val * val;
    }
    #pragma unroll
    for (int m = 1; m < 16; m <<= 1) {
      sum += __shfl_xor(sum, m, 64);
      sq += __shfl_xor(sq, m, 64);
    }
    float mu = sum * (1.f / 128.f);
    float var = sq * (1.f / 128.f) - mu * mu;
    float r = rsqrtf(var + 1e-5f);
    if (ok) {
      #pragma unroll
      for (int n = 0; n < 8; n++) {
        float y = fmaxf((vv[n] - mu) * r * gl8[n] + bl8[n], 0.f);
        xsT[(size_t)row * HID + n * 16 + (l & 15)] = f2bf(y);
      }
    }
  }
}

// ---------------- CSR build (deterministic, 4 ets fused) ----------------
__global__ __launch_bounds__(256) void csr_hist4(
    const int* __restrict__ d0, const int* __restrict__ d1,
    const int* __restrict__ d2, const int* __restrict__ d3,
    int* __restrict__ cnt) {
  int t = blockIdx.x * 256 + threadIdx.x;
  if (t >= 4 * E) return;
  int et = t / E, e = t - et * E;
  const int* dp = et == 0 ? d0 : et == 1 ? d1 : et == 2 ? d2 : d3;
  int base = et == 0 ? 0 : et == 1 ? NA : et == 2 ? 2 * NA : 2 * NA + NW;
  atomicAdd(&cnt[base + dp[e]], 1);
}

// fused per-256-block scan over all 4 et regions (grid partitioned by et)
__global__ __launch_bounds__(256) void scan_block_all(
    const int* __restrict__ cnt, int* __restrict__ rpAll,
    int* __restrict__ bsum) {
  const int nbA = (NA + 255) / 256, nbW = (NW + 255) / 256,
            nbO = (NO + 255) / 256;
  int bx = blockIdx.x;
  int et, bbase, cbase, rpo, n;
  if (bx < nbA) { et = 0; bbase = 0; cbase = 0; rpo = 0; n = NA; }
  else if (bx < 2 * nbA) { et = 1; bbase = nbA; cbase = NA; rpo = NA + 1; n = NA; }
  else if (bx < 2 * nbA + nbW) {
    et = 2; bbase = 2 * nbA; cbase = 2 * NA; rpo = 2 * (NA + 1); n = NW;
  } else {
    et = 3; bbase = 2 * nbA + nbW; cbase = 2 * NA + NW;
    rpo = 2 * (NA + 1) + (NW + 1); n = NO;
  }
  int lb = bx - bbase;
  __shared__ int tmp[256];
  int i = lb * 256 + threadIdx.x;
  int v = (i < n) ? cnt[cbase + i] : 0;
  tmp[threadIdx.x] = v;
  __syncthreads();
  int acc = v;
  for (int off = 1; off < 256; off <<= 1) {
    int other = (threadIdx.x >= off) ? tmp[threadIdx.x - off] : 0;
    __syncthreads();
    acc += other;
    tmp[threadIdx.x] = acc;
    __syncthreads();
  }
  if (i < n) rpAll[rpo + i] = acc - v;
  if (threadIdx.x == 255) bsum[et * 512 + lb] = acc;
}

// fused bsum scans: 4 blocks, one per et
__global__ __launch_bounds__(256) void scan_bsums_all(int* __restrict__ bsum) {
  int et = blockIdx.x;
  int nb = et < 2 ? (NA + 255) / 256 : (et == 2 ? (NW + 255) / 256
                                                : (NO + 255) / 256);
  int* bs = bsum + et * 512;
  __shared__ int tmp[256];
  __shared__ int carry;
  if (threadIdx.x == 0) carry = 0;
  __syncthreads();
  for (int start = 0; start < nb; start += 256) {
    int i = start + threadIdx.x;
    int v = (i < nb) ? bs[i] : 0;
    tmp[threadIdx.x] = v;
    __syncthreads();
    int acc = v;
    for (int off = 1; off < 256; off <<= 1) {
      int other = (threadIdx.x >= off) ? tmp[threadIdx.x - off] : 0;
      __syncthreads();
      acc += other;
      tmp[threadIdx.x] = acc;
      __syncthreads();
    }
    int c = carry;
    if (i < nb) bs[i] = c + acc - v;
    __syncthreads();
    if (threadIdx.x == 255) carry = c + acc;
    __syncthreads();
  }
}

__device__ __forceinline__ void et_of_node(int i, int& et, int& base, int& nd,
                                           int& rpo) {
  if (i < NA) { et = 0; base = 0; nd = NA; rpo = 0; }
  else if (i < 2 * NA) { et = 1; base = NA; nd = NA; rpo = NA + 1; }
  else if (i < 2 * NA + NW) { et = 2; base = 2 * NA; nd = NW; rpo = 2 * (NA + 1); }
  else { et = 3; base = 2 * NA + NW; nd = NO; rpo = 2 * (NA + 1) + NW + 1; }
}

__global__ __launch_bounds__(256) void csr_finalize4(
    int* __restrict__ rpAll, const int* __restrict__ bsum,
    int* __restrict__ cursor) {
  int i = blockIdx.x * 256 + threadIdx.x;
  if (i >= 2 * NA + NW + NO) return;
  int et, base, nd, rpo;
  et_of_node(i, et, base, nd, rpo);
  int local = i - base;
  int v = rpAll[rpo + local] + bsum[et * 512 + (local >> 8)];
  rpAll[rpo + local] = v;
  cursor[base + local] = v;
  if (local == 0) rpAll[rpo + nd] = E;
}

__global__ __launch_bounds__(256) void csr_scatter4(
    const int* __restrict__ d0, const int* __restrict__ d1,
    const int* __restrict__ d2, const int* __restrict__ d3,
    int* __restrict__ cursor, int* __restrict__ ceAll) {
  int t = blockIdx.x * 256 + threadIdx.x;
  if (t >= 4 * E) return;
  int et = t / E, e = t - et * E;
  const int* dp = et == 0 ? d0 : et == 1 ? d1 : et == 2 ? d2 : d3;
  int base = et == 0 ? 0 : et == 1 ? NA : et == 2 ? 2 * NA : 2 * NA + NW;
  int slot = atomicAdd(&cursor[base + dp[e]], 1);
  ceAll[(size_t)et * E + slot] = e;
}

__global__ __launch_bounds__(256) void csr_sort4(const int* __restrict__ rpAll,
                                                 int* __restrict__ ceAll) {
  int i = blockIdx.x * 256 + threadIdx.x;
  if (i >= 2 * NA + NW + NO) return;
  int et, base, nd, rpo;
  et_of_node(i, et, base, nd, rpo);
  int local = i - base;
  int b = rpAll[rpo + local], e = rpAll[rpo + local + 1];
  int* ce = ceAll + (size_t)et * E;
  for (int k = b + 1; k < e; k++) {
    int key = ce[k];
    int j = k - 1;
    while (j >= b && ce[j] > key) { ce[j + 1] = ce[j]; j--; }
    ce[j + 1] = key;
  }
}

// slot-ordered GLOBAL src node ids
__global__ __launch_bounds__(256) void build_sd(
    const int* __restrict__ ce, const int* __restrict__ s0,
    const int* __restrict__ s1, const int* __restrict__ s2,
    const int* __restrict__ s3, int* __restrict__ srcOf) {
  int t = blockIdx.x * 256 + threadIdx.x;
  if (t >= 4 * E) return;
  int et = t / E;
  int e = ce[t];
  const int* sp = et == 0 ? s0 : et == 1 ? s1 : et == 2 ? s2 : s3;
  int sOff = et == 0 ? NA : et == 1 ? NA + NW : 0;
  srcOf[t] = sOff + sp[e];
}

// ---------------- fused attention (online softmax, 2-wide pipelined) ------
// one 64-lane wave per dst; lane = dim-pair; quarter q = lane>>4 = head.
// 2-wide unrolled edge loop with 2-stage prefetch (rows t+2/t+3, idx t+4/t+5).
__global__ __launch_bounds__(256) void attn_fused(
    const unsigned short* __restrict__ kqv, const int* __restrict__ rpAll,
    const int* __restrict__ srcOf, const float* __restrict__ Pl,
    const float* __restrict__ Ml, unsigned short* __restrict__ out) {
  int dl = (blockIdx.x * 256 + threadIdx.x) >> 6;
  int lane = threadIdx.x & 63;
  if (dl >= NTOT) return;
  int q = lane >> 4, p = lane & 15;
  int b0, e0, b1 = 0, e1 = 0, et23 = -1;
  const int* so0;
  const int* so1 = srcOf;
  float ps0, ps1 = 0.f;
  if (dl < NA) {
    b0 = rpAll[dl]; e0 = rpAll[dl + 1];
    b1 = rpAll[(NA + 1) + dl]; e1 = rpAll[(NA + 1) + dl + 1];
    so0 = srcOf; so1 = srcOf + E;
    ps0 = Pl[q] * SCALE; ps1 = Pl[H + q] * SCALE;
  } else if (dl < NA + NW) {
    int x = dl - NA;
    b0 = rpAll[2 * (NA + 1) + x]; e0 = rpAll[2 * (NA + 1) + x + 1];
    so0 = srcOf + 2 * (size_t)E;
    ps0 = Pl[2 * H + q] * SCALE;
    et23 = 2;
  } else {
    int x = dl - NA - NW;
    b0 = rpAll[2 * (NA + 1) + (NW + 1) + x];
    e0 = rpAll[2 * (NA + 1) + (NW + 1) + x + 1];
    so0 = srcOf + 3 * (size_t)E;
    ps0 = Pl[3 * H + q] * SCALE;
    et23 = 3;
  }
  const int n0 = e0 - b0;
  const int n01 = n0 + (e1 - b1);
  auto srcAt = [&](int t) -> int {
    return (t < n0) ? so0[b0 + t] : so1[b1 + (t - n0)];
  };
  // q-row (one coalesced 256B load, stays in regs)
  unsigned qv = *(const unsigned*)(kqv + (size_t)dl * LDK + HID + lane * 2);
  float qx = blo(qv), qy = bhi(qv);
  const int lo2 = lane * 2;

  float m = -INFINITY, den = 0.f, ax = 0.f, ay = 0.f;
  // pipeline prologue: rows for edges 0,1; indices for 2,3
  unsigned ka = 0, va = 0, kb = 0, vb = 0;
  int i2 = 0, i3 = 0;
  if (n01 > 0) {
    const unsigned short* r = kqv + (size_t)srcAt(0) * LDK;
    ka = *(const unsigned*)(r + lo2);
    va = *(const unsigned*)(r + 2 * HID + lo2);
  }
  if (n01 > 1) {
    const unsigned short* r = kqv + (size_t)srcAt(1) * LDK;
    kb = *(const unsigned*)(r + lo2);
    vb = *(const unsigned*)(r + 2 * HID + lo2);
  }
  if (n01 > 2) i2 = srcAt(2);
  if (n01 > 3) i3 = srcAt(3);
  int t = 0;
  for (; t + 1 < n01; t += 2) {
    unsigned pka = ka, pva = va, pkb = kb, pvb = vb;
    float psa = (t < n0) ? ps0 : ps1;
    float psb = (t + 1 < n0) ? ps0 : ps1;
    // prefetch rows for t+2, t+3
    if (t + 2 < n01) {
      const unsigned short* r = kqv + (size_t)i2 * LDK;
      ka = *(const unsigned*)(r + lo2);
      va = *(const unsigned*)(r + 2 * HID + lo2);
    }
    if (t + 3 < n01) {
      const unsigned short* r = kqv + (size_t)i3 * LDK;
      kb = *(const unsigned*)(r + lo2);
      vb = *(const unsigned*)(r + 2 * HID + lo2);
    }
    // prefetch indices for t+4, t+5
    if (t + 4 < n01) i2 = srcAt(t + 4);
    if (t + 5 < n01) i3 = srcAt(t + 5);
    // compute pair (independent shfl chains -> ILP)
    float sa = qx * blo(pka) + qy * bhi(pka);
    float sb = qx * blo(pkb) + qy * bhi(pkb);
    sa += __shfl_xor(sa, 1, 64);
    sb += __shfl_xor(sb, 1, 64);
    sa += __shfl_xor(sa, 2, 64);
    sb += __shfl_xor(sb, 2, 64);
    sa += __shfl_xor(sa, 4, 64);
    sb += __shfl_xor(sb, 4, 64);
    sa += __shfl_xor(sa, 8, 64);
    sb += __shfl_xor(sb, 8, 64);
    sa *= psa;
    sb *= psb;
    float nm = fmaxf(m, fmaxf(sa, sb));
    float c = __expf(m - nm);
    float wa = __expf(sa - nm), wb = __expf(sb - nm);
    den = den * c + wa + wb;
    ax = ax * c + wa * blo(pva) + wb * blo(pvb);
    ay = ay * c + wa * bhi(pva) + wb * bhi(pvb);
    m = nm;
  }
  if (t < n01) {  // odd tail (rows already in ka/va)
    float ps = (t < n0) ? ps0 : ps1;
    float s = qx * blo(ka) + qy * bhi(ka);
    s += __shfl_xor(s, 1, 64);
    s += __shfl_xor(s, 2, 64);
    s += __shfl_xor(s, 4, 64);
    s += __shfl_xor(s, 8, 64);
    s *= ps;
    float nm = fmaxf(m, s);
    float c = __expf(m - nm);
    float w = __expf(s - nm);
    den = den * c + w;
    ax = ax * c + w * blo(va);
    ay = ay * c + w * bhi(va);
  }
  float inv = 1.f / (den + 1e-16f);
  ax *= inv;
  ay *= inv;
  // W/O dst: M transform (raw-v aggregated; apply per-dst once)
  if (et23 >= 0) {
    const float* Mm = Ml + ((size_t)et23 * H + q) * D * D;
    int base = lane & 48;
    float o0 = 0.f, o1 = 0.f;
    #pragma unroll
    for (int j = 0; j < 16; j++) {
      float s0 = __shfl(ax, base + j, 64);
      float s1 = __shfl(ay, base + j, 64);
      float2 m0 = *(const float2*)&Mm[(2 * j) * 32 + 2 * p];
      float2 m1 = *(const float2*)&Mm[(2 * j + 1) * 32 + 2 * p];
      o0 += s0 * m0.x + s1 * m1.x;
      o1 += s0 * m0.y + s1 * m1.y;
    }
    ax = o0; ay = o1;
  }
  unsigned ov = (unsigned)f2bf(gelu_exact(ax)) |
                ((unsigned)f2bf(gelu_exact(ay)) << 16);
  *(unsigned*)(out + (size_t)dl * LDK + HID + lane * 2) = ov;
}

__global__ __launch_bounds__(256) void head_kernel(
    const unsigned short* __restrict__ xs0, const float* __restrict__ w_head,
    const float* __restrict__ b_head, const float* __restrict__ basep,
    float* __restrict__ out, int Nrows) {
  int wid = (blockIdx.x * 256 + threadIdx.x) >> 6;
  int lane = threadIdx.x & 63;
  if (wid >= Nrows) return;
  size_t base = (size_t)wid * HID;
  float d = bf2f(xs0[base + lane]) * w_head[lane] +
            bf2f(xs0[base + 64 + lane]) * w_head[64 + lane];
  #pragma unroll
  for (int m = 1; m < 64; m <<= 1) d += __shfl_xor(d, m, 64);
  if (lane == 0) out[wid] = basep[0] + b_head[0] + d;
}

}  // namespace

extern "C" void kernel_launch(void* const* d_in, const int* in_sizes, int n_in,
                              void* d_out, int out_size, void* d_ws,
                              size_t ws_size, hipStream_t stream) {
  const float* x_a = (const float*)d_in[0];
  const float* x_w = (const float*)d_in[1];
  const float* x_o = (const float*)d_in[2];
  const float* W_in = (const float*)d_in[3];
  const float* b_in = (const float*)d_in[4];
  const float* W_kqv = (const float*)d_in[5];
  const float* b_kqv = (const float*)d_in[6];
  const float* a_rel = (const float*)d_in[7];
  const float* m_rel = (const float*)d_in[8];
  const float* p_rel = (const float*)d_in[9];
  const float* skip_p = (const float*)d_in[10];
  const float* W_o = (const float*)d_in[11];
  const float* b_o = (const float*)d_in[12];
  const float* ln_g = (const float*)d_in[13];
  const float* ln_b = (const float*)d_in[14];
  const float* w_head = (const float*)d_in[15];
  const float* b_head = (const float*)d_in[16];
  const float* basep = (const float*)d_in[17];
  const int* srcs[4] = {(const int*)d_in[18], (const int*)d_in[20],
                        (const int*)d_in[22], (const int*)d_in[24]};
  const int* dsts[4] = {(const int*)d_in[19], (const int*)d_in[21],
                        (const int*)d_in[23], (const int*)d_in[25]};

  // ---- workspace layout (~183 MB) ----
  const size_t SZ_XS = (size_t)NTOT * HID * 2;
  const size_t SZ_KQV = (size_t)NTOT * LDK * 2;
  const size_t SZ_WINT = (size_t)3 * 128 * 64 * 2;
  const size_t SZ_WK0T = (size_t)2 * 384 * 128 * 2;
  const size_t SZ_WOT = (size_t)6 * 128 * 128 * 2;
  const size_t SZ_WET = (size_t)2 * 384 * 128 * 2;
  const size_t SZ_BE = ((size_t)2 * 384 * 4 + 63) & ~63ull;
  const size_t SZ_SD = (size_t)4 * E * 4;
  const int CNT_TOT = 2 * NA + NW + NO;
  const int RP_TOT = 2 * (NA + 1) + (NW + 1) + (NO + 1);
  const size_t SZ_RP = ((size_t)RP_TOT * 4 + 63) & ~63ull;
  const size_t SZ_CE = (size_t)4 * E * 4;
  const size_t SZ_CU = ((size_t)CNT_TOT * 4 + 63) & ~63ull;
  const size_t SZ_BS = 4 * 512 * 4;
  const size_t need = SZ_XS + SZ_KQV + SZ_WINT + SZ_WK0T + SZ_WOT + SZ_WET +
                      SZ_BE + SZ_SD + SZ_RP + SZ_CE + 2 * SZ_CU + SZ_BS;
  if (ws_size < need) return;

  char* p = (char*)d_ws;
  unsigned short* xs = (unsigned short*)p;    p += SZ_XS;
  unsigned short* kqvB = (unsigned short*)p;  p += SZ_KQV;
  unsigned short* WinT = (unsigned short*)p;  p += SZ_WINT;
  unsigned short* Wk0T = (unsigned short*)p;  p += SZ_WK0T;
  unsigned short* WoT = (unsigned short*)p;   p += SZ_WOT;
  unsigned short* WeT = (unsigned short*)p;   p += SZ_WET;
  float* beB = (float*)p;                     p += SZ_BE;
  int* srcOf = (int*)p;                       p += SZ_SD;
  int* rpAll = (int*)p;                       p += SZ_RP;
  int* ceAll = (int*)p;                       p += SZ_CE;
  int* cursor = (int*)p;                      p += SZ_CU;
  int* cnt = (int*)p;                         p += SZ_CU;
  int* bsum = (int*)p;

  const int CNTT = 2 * NA + NW + NO;
  const int e4b = (4 * E + 255) / 256;
  const int nb0 = (NA + 63) / 64, nb01 = nb0 + (NW + 63) / 64;
  const int nbTot = nb01 + (NO + 63) / 64;
  const int nbA = (NA + 255) / 256, nbW = (NW + 255) / 256,
            nbO = (NO + 255) / 256;

  // ---- CSR build (once) ----
  hipMemsetAsync(cnt, 0, (size_t)CNTT * 4, stream);
  csr_hist4<<<e4b, 256, 0, stream>>>(dsts[0], dsts[1], dsts[2], dsts[3], cnt);
  scan_block_all<<<2 * nbA + nbW + nbO, 256, 0, stream>>>(cnt, rpAll, bsum);
  scan_bsums_all<<<4, 256, 0, stream>>>(bsum);
  csr_finalize4<<<(CNTT + 255) / 256, 256, 0, stream>>>(rpAll, bsum, cursor);
  csr_scatter4<<<e4b, 256, 0, stream>>>(dsts[0], dsts[1], dsts[2], dsts[3],
                                        cursor, ceAll);
  csr_sort4<<<(CNTT + 255) / 256, 256, 0, stream>>>(rpAll, ceAll);
  build_sd<<<e4b, 256, 0, stream>>>(ceAll, srcs[0], srcs[1], srcs[2], srcs[3],
                                    srcOf);

  // ---- weight prep + input projection ----
  prep_weights<<<(3 * 128 * 64 + 2 * 384 * 128 + 6 * 128 * 128 + 255) / 256,
                 256, 0, stream>>>(W_in, W_kqv, W_o, WinT, Wk0T, WoT);
  in_fused<<<nbTot, 256, 0, stream>>>(x_a, x_w, x_o, WinT, b_in, xs, nb0, nb01);

  const size_t DD = (size_t)H * D * D;
  for (int l = 0; l < 2; l++) {
    const float* Al = a_rel + (size_t)l * 4 * DD;
    const float* Ml = m_rel + (size_t)l * 4 * DD;
    const float* Pl = p_rel + (size_t)l * 4 * H;
    const float* Wl = W_kqv + (size_t)l * 3 * HID * LDK;
    const float* bl = b_kqv + (size_t)l * 3 * LDK;
    fold_weights<<<(2 * 128 * 384 + 2 * 384 + 255) / 256, 256, 0, stream>>>(
        Wl, bl, Al, Ml, WeT, beB);
    kqv_fused<<<dim3(nbTot, 3), 256, 0, stream>>>(
        xs, Wk0T + (size_t)l * 384 * 128, bl, WeT, beB, kqvB, nb0, nb01);
    attn_fused<<<(NTOT + 3) / 4, 256, 0, stream>>>(kqvB, rpAll, srcOf, Pl, Ml,
                                                   kqvB);
    wo_ln_fused<<<nbTot, 256, 0, stream>>>(
        kqvB, WoT + (size_t)l * 3 * 128 * 128, b_o + (size_t)l * 3 * HID, xs,
        skip_p + l * 3, ln_g + (size_t)l * 3 * HID, ln_b + (size_t)l * 3 * HID,
        nb0, nb01);
  }
  head_kernel<<<(NA + 3) / 4, 256, 0, stream>>>(xs, w_head, b_head, basep,
                                                (float*)d_out, NA);
}

// Round 19
// 703.779 us; speedup vs baseline: 1.0914x; 1.0098x over previous
//
#include <hip/hip_runtime.h>
#include <cstddef>
#include <cmath>

namespace {

constexpr int H = 4, D = 32, HID = 128;
constexpr int NA = 100000, NW = 20000, NO = 50000;
constexpr int NTOT = NA + NW + NO;
constexpr int E = 150000;
constexpr float SCALE = 0.17677669529663687f;  // 1/sqrt(32)
constexpr int LDK = 3 * HID;  // kqv row stride (384)

typedef __attribute__((ext_vector_type(8))) short short8v;
typedef __attribute__((ext_vector_type(4))) float f32x4;

__device__ __forceinline__ float gelu_exact(float x) {
  return 0.5f * x * (1.f + erff(x * 0.7071067811865475f));
}
__device__ __forceinline__ unsigned short f2bf(float f) {  // RNE
  unsigned u = __float_as_uint(f);
  return (unsigned short)((u + 0x7FFF + ((u >> 16) & 1)) >> 16);
}
__device__ __forceinline__ float bf2f(unsigned short s) {
  return __uint_as_float(((unsigned)s) << 16);
}
__device__ __forceinline__ float blo(unsigned w) {
  return __uint_as_float(w << 16);
}
__device__ __forceinline__ float bhi(unsigned w) {
  return __uint_as_float(w & 0xFFFF0000u);
}

__device__ __forceinline__ int btype(int bx, int nb0, int nb01) {
  return bx < nb0 ? 0 : (bx < nb01 ? 1 : 2);
}

// ---------------- swizzled BK=64 MFMA GEMM body ----------------
template <int KSTEPS, bool A_FP32>
__device__ __forceinline__ void gemm_body(
    const void* __restrict__ Av, int lda, const unsigned short* __restrict__ BT,
    int ldb, f32x4* acc, int M, int bm) {
  __shared__ unsigned short As[64 * 64];
  __shared__ unsigned short Bs[128 * 64];
  const int tid = threadIdx.x;
  const int wv = tid >> 6, l = tid & 63;
  for (int ks = 0; ks < KSTEPS; ks++) {
    const int kk = ks * 64;
    #pragma unroll
    for (int p = 0; p < 2; p++) {
      int idx = tid + p * 256;
      int r = idx >> 3, c = idx & 7;
      int gr = bm + r;
      unsigned short tmp[8] = {0, 0, 0, 0, 0, 0, 0, 0};
      if (gr < M) {
        if (A_FP32) {
          const float* src = (const float*)Av + (size_t)gr * lda + kk + c * 8;
          float4 f0 = *(const float4*)src;
          float4 f1 = *(const float4*)(src + 4);
          tmp[0] = f2bf(f0.x); tmp[1] = f2bf(f0.y);
          tmp[2] = f2bf(f0.z); tmp[3] = f2bf(f0.w);
          tmp[4] = f2bf(f1.x); tmp[5] = f2bf(f1.y);
          tmp[6] = f2bf(f1.z); tmp[7] = f2bf(f1.w);
        } else {
          *(uint4*)tmp = *(const uint4*)((const unsigned short*)Av +
                                         (size_t)gr * lda + kk + c * 8);
        }
      }
      *(uint4*)&As[r * 64 + ((c ^ (r & 7)) * 8)] = *(const uint4*)tmp;
    }
    #pragma unroll
    for (int p = 0; p < 4; p++) {
      int idx = tid + p * 256;
      int r = idx >> 3, c = idx & 7;
      uint4 v = *(const uint4*)(BT + (size_t)r * ldb + kk + c * 8);
      *(uint4*)&Bs[r * 64 + ((c ^ (r & 7)) * 8)] = v;
    }
    __syncthreads();
    const int arow = wv * 16 + (l & 15);
    #pragma unroll
    for (int ksub = 0; ksub < 2; ksub++) {
      int ch = ksub * 4 + (l >> 4);
      short8v af = *(const short8v*)&As[arow * 64 + ((ch ^ (arow & 7)) * 8)];
      #pragma unroll
      for (int n = 0; n < 8; n++) {
        int brow = n * 16 + (l & 15);
        short8v bf =
            *(const short8v*)&Bs[brow * 64 + ((ch ^ (brow & 7)) * 8)];
        acc[n] =
            __builtin_amdgcn_mfma_f32_16x16x32_bf16(af, bf, acc[n], 0, 0, 0);
      }
    }
    __syncthreads();
  }
}

// ---------------- weight prep: bf16 transposed copies ----------------
__global__ __launch_bounds__(256) void prep_weights(
    const float* __restrict__ W_in, const float* __restrict__ W_kqv,
    const float* __restrict__ W_o, unsigned short* __restrict__ WinT,
    unsigned short* __restrict__ Wk0T, unsigned short* __restrict__ WoT) {
  int idx = blockIdx.x * 256 + threadIdx.x;
  const int N1 = 3 * 128 * 64, N2 = 2 * 384 * 128, N3 = 6 * 128 * 128;
  if (idx < N1) {
    int t = idx / 8192, rem = idx - t * 8192;
    int n = rem >> 6, k = rem & 63;
    WinT[idx] = f2bf(W_in[(size_t)t * 64 * 128 + (size_t)k * 128 + n]);
  } else if (idx < N1 + N2) {
    int r = idx - N1;
    int lyr = r / (384 * 128), rem = r - lyr * (384 * 128);
    int n = rem >> 7, k = rem & 127;
    Wk0T[r] = f2bf(W_kqv[(size_t)lyr * 3 * 128 * 384 + (size_t)k * 384 + n]);
  } else if (idx < N1 + N2 + N3) {
    int r = idx - N1 - N2;
    int lt = r / (128 * 128), rem = r - lt * (128 * 128);
    int n = rem >> 7, k = rem & 127;
    WoT[r] = f2bf(W_o[(size_t)lt * 128 * 128 + (size_t)k * 128 + n]);
  }
}

// ---------------- weight folding (BOTH layers; y = layer) ----------------
__global__ __launch_bounds__(256) void fold_weights2(
    const float* __restrict__ W_kqv, const float* __restrict__ b_kqv,
    const float* __restrict__ a_rel, const float* __restrict__ m_rel,
    unsigned short* __restrict__ WeT, float* __restrict__ be) {
  const int lyr = blockIdx.y;
  const size_t DD = (size_t)H * D * D;
  const float* Wl = W_kqv + (size_t)lyr * 3 * HID * LDK;
  const float* bl = b_kqv + (size_t)lyr * 3 * LDK;
  const float* Al = a_rel + (size_t)lyr * 4 * DD;
  const float* Ml = m_rel + (size_t)lyr * 4 * DD;
  unsigned short* WeTl = WeT + (size_t)lyr * 2 * 384 * 128;
  float* bel = be + (size_t)lyr * 2 * 384;
  int idx = blockIdx.x * 256 + threadIdx.x;
  const int NW_ = 2 * 128 * 384;
  if (idx < NW_) {
    int tt = idx / (128 * 384);
    int rem = idx - tt * (128 * 384);
    int r = rem / 384, c = rem - r * 384;
    int slice = c >> 7, h = (c >> 5) & 3, j = c & 31;
    const float* Wsrc = Wl + (size_t)(tt + 1) * 128 * 384 + (size_t)r * 384;
    float acc = 0.f;
    if (slice == 0) {
      const float* A = Al + ((size_t)tt * H + h) * D * D;
      for (int d = 0; d < 32; d++) acc += Wsrc[h * 32 + d] * A[d * 32 + j];
    } else if (slice == 1) {
      const float* A = Al + ((size_t)(2 + tt) * H + h) * D * D;
      for (int e = 0; e < 32; e++)
        acc += Wsrc[128 + h * 32 + e] * A[j * 32 + e];
    } else {
      const float* Mm = Ml + ((size_t)tt * H + h) * D * D;
      for (int d = 0; d < 32; d++)
        acc += Wsrc[256 + h * 32 + d] * Mm[d * 32 + j];
    }
    WeTl[(size_t)tt * 384 * 128 + (size_t)c * 128 + r] = f2bf(acc);
  } else if (idx < NW_ + 2 * 384) {
    int rem = idx - NW_;
    int tt = rem / 384, c = rem - tt * 384;
    int slice = c >> 7, h = (c >> 5) & 3, j = c & 31;
    const float* bsrc = bl + (size_t)(tt + 1) * 384;
    float acc = 0.f;
    if (slice == 0) {
      const float* A = Al + ((size_t)tt * H + h) * D * D;
      for (int d = 0; d < 32; d++) acc += bsrc[h * 32 + d] * A[d * 32 + j];
    } else if (slice == 1) {
      const float* A = Al + ((size_t)(2 + tt) * H + h) * D * D;
      for (int e = 0; e < 32; e++)
        acc += bsrc[128 + h * 32 + e] * A[j * 32 + e];
    } else {
      const float* Mm = Ml + ((size_t)tt * H + h) * D * D;
      for (int d = 0; d < 32; d++)
        acc += bsrc[256 + h * 32 + d] * Mm[d * 32 + j];
    }
    bel[rem] = acc;
  }
}

// input proj: xs = relu(x @ W_in[t] + b_in[t])
__global__ __launch_bounds__(256) void in_fused(
    const float* __restrict__ xa, const float* __restrict__ xw,
    const float* __restrict__ xo, const unsigned short* __restrict__ WinT,
    const float* __restrict__ b_in, unsigned short* __restrict__ xs, int nb0,
    int nb01) {
  int t = btype(blockIdx.x, nb0, nb01);
  int base = t == 0 ? 0 : (t == 1 ? nb0 : nb01);
  int M = t == 0 ? NA : (t == 1 ? NW : NO);
  int off = t == 0 ? 0 : (t == 1 ? NA : NA + NW);
  const float* A = t == 0 ? xa : (t == 1 ? xw : xo);
  const int bm = (blockIdx.x - base) * 64;
  f32x4 acc[8] = {};
  gemm_body<1, true>(A, 64, WinT + (size_t)t * 128 * 64, 64, acc, M, bm);
  const int l = threadIdx.x & 63, wv = threadIdx.x >> 6;
  const float* bias = b_in + t * HID;
  unsigned short* C = xs + (size_t)off * HID;
  #pragma unroll
  for (int n = 0; n < 8; n++) {
    int col = n * 16 + (l & 15);
    float bb = bias[col];
    #pragma unroll
    for (int j = 0; j < 4; j++) {
      int row = bm + wv * 16 + (l >> 4) * 4 + j;
      if (row < M) C[(size_t)row * HID + col] = f2bf(fmaxf(acc[n][j] + bb, 0.f));
    }
  }
}

// kqv proj: t=0 raw Wk0T; t=1,2 folded WeT. 64x128 tile, y = col-tile (3).
__global__ __launch_bounds__(256) void kqv_fused(
    const unsigned short* __restrict__ xs, const unsigned short* __restrict__ Wk0Tl,
    const float* __restrict__ b0, const unsigned short* __restrict__ WeT,
    const float* __restrict__ be, unsigned short* __restrict__ kqvB, int nb0,
    int nb01) {
  int t = btype(blockIdx.x, nb0, nb01);
  int base = t == 0 ? 0 : (t == 1 ? nb0 : nb01);
  int M = t == 0 ? NA : (t == 1 ? NW : NO);
  int off = t == 0 ? 0 : (t == 1 ? NA : NA + NW);
  const unsigned short* BT =
      (t == 0 ? Wk0Tl : WeT + (size_t)(t - 1) * 384 * 128);
  const float* bias = t == 0 ? b0 : be + (size_t)(t - 1) * 384;
  const int bm = (blockIdx.x - base) * 64;
  const int bn = blockIdx.y * 128;
  f32x4 acc[8] = {};
  gemm_body<2, false>(xs + (size_t)off * HID, HID, BT + (size_t)bn * 128, 128,
                      acc, M, bm);
  const int l = threadIdx.x & 63, wv = threadIdx.x >> 6;
  unsigned short* C = kqvB + (size_t)off * LDK;
  #pragma unroll
  for (int n = 0; n < 8; n++) {
    int col = bn + n * 16 + (l & 15);
    float bb = bias[col];
    #pragma unroll
    for (int j = 0; j < 4; j++) {
      int row = bm + wv * 16 + (l >> 4) * 4 + j;
      if (row < M) C[(size_t)row * LDK + col] = f2bf(acc[n][j] + bb);
    }
  }
}

// fused: xs = relu(LN( g*(agg_gelu @ W_o + b_o) + (1-g)*xs ))
__global__ __launch_bounds__(256) void wo_ln_fused(
    const unsigned short* __restrict__ kqvB, const unsigned short* __restrict__ WoTl,
    const float* __restrict__ bl, unsigned short* __restrict__ xs,
    const float* __restrict__ skipl, const float* __restrict__ gll,
    const float* __restrict__ bll, int nb0, int nb01) {
  int t = btype(blockIdx.x, nb0, nb01);
  int base = t == 0 ? 0 : (t == 1 ? nb0 : nb01);
  int M = t == 0 ? NA : (t == 1 ? NW : NO);
  int off = t == 0 ? 0 : (t == 1 ? NA : NA + NW);
  const int bm = (blockIdx.x - base) * 64;
  f32x4 acc[8] = {};
  gemm_body<2, false>(kqvB + (size_t)off * LDK + HID, LDK,
                      WoTl + (size_t)t * 128 * 128, 128, acc, M, bm);
  const int l = threadIdx.x & 63, wv = threadIdx.x >> 6;
  const float* bias = bl + t * HID;
  const float* gln = gll + t * HID;
  const float* bln = bll + t * HID;
  unsigned short* xsT = xs + (size_t)off * HID;
  const float g = 1.f / (1.f + expf(-skipl[t]));
  float bb[8], gl8[8], bl8[8];
  #pragma unroll
  for (int n = 0; n < 8; n++) {
    int col = n * 16 + (l & 15);
    bb[n] = bias[col];
    gl8[n] = gln[col];
    bl8[n] = bln[col];
  }
  #pragma unroll
  for (int j = 0; j < 4; j++) {
    int row = bm + wv * 16 + (l >> 4) * 4 + j;
    bool ok = row < M;
    float vv[8], sum = 0.f, sq = 0.f;
    #pragma unroll
    for (int n = 0; n < 8; n++) {
      int col = n * 16 + (l & 15);
      float xo = ok ? bf2f(xsT[(size_t)row * HID + col]) : 0.f;
      float val = g * (acc[n][j] + bb[n]) + (1.f - g) * xo;
      vv[n] = val;
      sum += val;
      sq += val * val;
    }
    #pragma unroll
    for (int m = 1; m < 16; m <<= 1) {
      sum += __shfl_xor(sum, m, 64);
      sq += __shfl_xor(sq, m, 64);
    }
    float mu = sum * (1.f / 128.f);
    float var = sq * (1.f / 128.f) - mu * mu;
    float r = rsqrtf(var + 1e-5f);
    if (ok) {
      #pragma unroll
      for (int n = 0; n < 8; n++) {
        float y = fmaxf((vv[n] - mu) * r * gl8[n] + bl8[n], 0.f);
        xsT[(size_t)row * HID + n * 16 + (l & 15)] = f2bf(y);
      }
    }
  }
}

// ---------------- CSR build (deterministic, 4 ets fused) ----------------
__global__ __launch_bounds__(256) void csr_hist4(
    const int* __restrict__ d0, const int* __restrict__ d1,
    const int* __restrict__ d2, const int* __restrict__ d3,
    int* __restrict__ cnt) {
  int t = blockIdx.x * 256 + threadIdx.x;
  if (t >= 4 * E) return;
  int et = t / E, e = t - et * E;
  const int* dp = et == 0 ? d0 : et == 1 ? d1 : et == 2 ? d2 : d3;
  int base = et == 0 ? 0 : et == 1 ? NA : et == 2 ? 2 * NA : 2 * NA + NW;
  atomicAdd(&cnt[base + dp[e]], 1);
}

// fused per-256-block scan over all 4 et regions (grid partitioned by et)
__global__ __launch_bounds__(256) void scan_block_all(
    const int* __restrict__ cnt, int* __restrict__ rpAll,
    int* __restrict__ bsum) {
  const int nbA = (NA + 255) / 256, nbW = (NW + 255) / 256,
            nbO = (NO + 255) / 256;
  int bx = blockIdx.x;
  int et, bbase, cbase, rpo, n;
  if (bx < nbA) { et = 0; bbase = 0; cbase = 0; rpo = 0; n = NA; }
  else if (bx < 2 * nbA) { et = 1; bbase = nbA; cbase = NA; rpo = NA + 1; n = NA; }
  else if (bx < 2 * nbA + nbW) {
    et = 2; bbase = 2 * nbA; cbase = 2 * NA; rpo = 2 * (NA + 1); n = NW;
  } else {
    et = 3; bbase = 2 * nbA + nbW; cbase = 2 * NA + NW;
    rpo = 2 * (NA + 1) + (NW + 1); n = NO;
  }
  int lb = bx - bbase;
  __shared__ int tmp[256];
  int i = lb * 256 + threadIdx.x;
  int v = (i < n) ? cnt[cbase + i] : 0;
  tmp[threadIdx.x] = v;
  __syncthreads();
  int acc = v;
  for (int off = 1; off < 256; off <<= 1) {
    int other = (threadIdx.x >= off) ? tmp[threadIdx.x - off] : 0;
    __syncthreads();
    acc += other;
    tmp[threadIdx.x] = acc;
    __syncthreads();
  }
  if (i < n) rpAll[rpo + i] = acc - v;
  if (threadIdx.x == 255) bsum[et * 512 + lb] = acc;
}

// fused bsum scans: 4 blocks, one per et
__global__ __launch_bounds__(256) void scan_bsums_all(int* __restrict__ bsum) {
  int et = blockIdx.x;
  int nb = et < 2 ? (NA + 255) / 256 : (et == 2 ? (NW + 255) / 256
                                                : (NO + 255) / 256);
  int* bs = bsum + et * 512;
  __shared__ int tmp[256];
  __shared__ int carry;
  if (threadIdx.x == 0) carry = 0;
  __syncthreads();
  for (int start = 0; start < nb; start += 256) {
    int i = start + threadIdx.x;
    int v = (i < nb) ? bs[i] : 0;
    tmp[threadIdx.x] = v;
    __syncthreads();
    int acc = v;
    for (int off = 1; off < 256; off <<= 1) {
      int other = (threadIdx.x >= off) ? tmp[threadIdx.x - off] : 0;
      __syncthreads();
      acc += other;
      tmp[threadIdx.x] = acc;
      __syncthreads();
    }
    int c = carry;
    if (i < nb) bs[i] = c + acc - v;
    __syncthreads();
    if (threadIdx.x == 255) carry = c + acc;
    __syncthreads();
  }
}

__device__ __forceinline__ void et_of_node(int i, int& et, int& base, int& nd,
                                           int& rpo) {
  if (i < NA) { et = 0; base = 0; nd = NA; rpo = 0; }
  else if (i < 2 * NA) { et = 1; base = NA; nd = NA; rpo = NA + 1; }
  else if (i < 2 * NA + NW) { et = 2; base = 2 * NA; nd = NW; rpo = 2 * (NA + 1); }
  else { et = 3; base = 2 * NA + NW; nd = NO; rpo = 2 * (NA + 1) + NW + 1; }
}

__global__ __launch_bounds__(256) void csr_finalize4(
    int* __restrict__ rpAll, const int* __restrict__ bsum,
    int* __restrict__ cursor) {
  int i = blockIdx.x * 256 + threadIdx.x;
  if (i >= 2 * NA + NW + NO) return;
  int et, base, nd, rpo;
  et_of_node(i, et, base, nd, rpo);
  int local = i - base;
  int v = rpAll[rpo + local] + bsum[et * 512 + (local >> 8)];
  rpAll[rpo + local] = v;
  cursor[base + local] = v;
  if (local == 0) rpAll[rpo + nd] = E;
}

__global__ __launch_bounds__(256) void csr_scatter4(
    const int* __restrict__ d0, const int* __restrict__ d1,
    const int* __restrict__ d2, const int* __restrict__ d3,
    int* __restrict__ cursor, int* __restrict__ ceAll) {
  int t = blockIdx.x * 256 + threadIdx.x;
  if (t >= 4 * E) return;
  int et = t / E, e = t - et * E;
  const int* dp = et == 0 ? d0 : et == 1 ? d1 : et == 2 ? d2 : d3;
  int base = et == 0 ? 0 : et == 1 ? NA : et == 2 ? 2 * NA : 2 * NA + NW;
  int slot = atomicAdd(&cursor[base + dp[e]], 1);
  ceAll[(size_t)et * E + slot] = e;
}

__global__ __launch_bounds__(256) void csr_sort4(const int* __restrict__ rpAll,
                                                 int* __restrict__ ceAll) {
  int i = blockIdx.x * 256 + threadIdx.x;
  if (i >= 2 * NA + NW + NO) return;
  int et, base, nd, rpo;
  et_of_node(i, et, base, nd, rpo);
  int local = i - base;
  int b = rpAll[rpo + local], e = rpAll[rpo + local + 1];
  int* ce = ceAll + (size_t)et * E;
  for (int k = b + 1; k < e; k++) {
    int key = ce[k];
    int j = k - 1;
    while (j >= b && ce[j] > key) { ce[j + 1] = ce[j]; j--; }
    ce[j + 1] = key;
  }
}

// slot-ordered GLOBAL src node ids
__global__ __launch_bounds__(256) void build_sd(
    const int* __restrict__ ce, const int* __restrict__ s0,
    const int* __restrict__ s1, const int* __restrict__ s2,
    const int* __restrict__ s3, int* __restrict__ srcOf) {
  int t = blockIdx.x * 256 + threadIdx.x;
  if (t >= 4 * E) return;
  int et = t / E;
  int e = ce[t];
  const int* sp = et == 0 ? s0 : et == 1 ? s1 : et == 2 ? s2 : s3;
  int sOff = et == 0 ? NA : et == 1 ? NA + NW : 0;
  srcOf[t] = sOff + sp[e];
}

// packed per-dst edge ranges: desc[dl] = (b0, e0, b1, e1); W/O: b1=e1=0
__global__ __launch_bounds__(256) void build_desc(const int* __restrict__ rpAll,
                                                  int4* __restrict__ desc) {
  int dl = blockIdx.x * 256 + threadIdx.x;
  if (dl >= NTOT) return;
  int4 d;
  if (dl < NA) {
    d.x = rpAll[dl]; d.y = rpAll[dl + 1];
    d.z = rpAll[(NA + 1) + dl]; d.w = rpAll[(NA + 1) + dl + 1];
  } else if (dl < NA + NW) {
    int x = dl - NA;
    d.x = rpAll[2 * (NA + 1) + x]; d.y = rpAll[2 * (NA + 1) + x + 1];
    d.z = 0; d.w = 0;
  } else {
    int x = dl - NA - NW;
    d.x = rpAll[2 * (NA + 1) + (NW + 1) + x];
    d.y = rpAll[2 * (NA + 1) + (NW + 1) + x + 1];
    d.z = 0; d.w = 0;
  }
  desc[dl] = d;
}

// ---------------- fused attention (online softmax, 2-wide pipelined) ------
// one 64-lane wave per dst; lane = dim-pair; quarter q = lane>>4 = head.
// packed desc -> one 16B range load; 2-stage prefetch.
__global__ __launch_bounds__(256) void attn_fused(
    const unsigned short* __restrict__ kqv, const int4* __restrict__ desc,
    const int* __restrict__ srcOf, const float* __restrict__ Pl,
    const float* __restrict__ Ml, unsigned short* __restrict__ out) {
  int dl = (blockIdx.x * 256 + threadIdx.x) >> 6;
  int lane = threadIdx.x & 63;
  if (dl >= NTOT) return;
  int q = lane >> 4, p = lane & 15;
  int4 dd = desc[dl];
  int b0 = dd.x, e0 = dd.y, b1 = dd.z, e1 = dd.w;
  int et23 = -1;
  const int* so0;
  const int* so1 = srcOf;
  float ps0, ps1 = 0.f;
  if (dl < NA) {
    so0 = srcOf; so1 = srcOf + E;
    ps0 = Pl[q] * SCALE; ps1 = Pl[H + q] * SCALE;
  } else if (dl < NA + NW) {
    so0 = srcOf + 2 * (size_t)E;
    ps0 = Pl[2 * H + q] * SCALE;
    et23 = 2;
  } else {
    so0 = srcOf + 3 * (size_t)E;
    ps0 = Pl[3 * H + q] * SCALE;
    et23 = 3;
  }
  const int n0 = e0 - b0;
  const int n01 = n0 + (e1 - b1);
  auto srcAt = [&](int t) -> int {
    return (t < n0) ? so0[b0 + t] : so1[b1 + (t - n0)];
  };
  // q-row (one coalesced 256B load, stays in regs)
  unsigned qv = *(const unsigned*)(kqv + (size_t)dl * LDK + HID + lane * 2);
  float qx = blo(qv), qy = bhi(qv);
  const int lo2 = lane * 2;

  float m = -INFINITY, den = 0.f, ax = 0.f, ay = 0.f;
  // pipeline prologue: rows for edges 0,1; indices for 2,3
  unsigned ka = 0, va = 0, kb = 0, vb = 0;
  int i2 = 0, i3 = 0;
  if (n01 > 0) {
    const unsigned short* r = kqv + (size_t)srcAt(0) * LDK;
    ka = *(const unsigned*)(r + lo2);
    va = *(const unsigned*)(r + 2 * HID + lo2);
  }
  if (n01 > 1) {
    const unsigned short* r = kqv + (size_t)srcAt(1) * LDK;
    kb = *(const unsigned*)(r + lo2);
    vb = *(const unsigned*)(r + 2 * HID + lo2);
  }
  if (n01 > 2) i2 = srcAt(2);
  if (n01 > 3) i3 = srcAt(3);
  int t = 0;
  for (; t + 1 < n01; t += 2) {
    unsigned pka = ka, pva = va, pkb = kb, pvb = vb;
    float psa = (t < n0) ? ps0 : ps1;
    float psb = (t + 1 < n0) ? ps0 : ps1;
    // prefetch rows for t+2, t+3
    if (t + 2 < n01) {
      const unsigned short* r = kqv + (size_t)i2 * LDK;
      ka = *(const unsigned*)(r + lo2);
      va = *(const unsigned*)(r + 2 * HID + lo2);
    }
    if (t + 3 < n01) {
      const unsigned short* r = kqv + (size_t)i3 * LDK;
      kb = *(const unsigned*)(r + lo2);
      vb = *(const unsigned*)(r + 2 * HID + lo2);
    }
    // prefetch indices for t+4, t+5
    if (t + 4 < n01) i2 = srcAt(t + 4);
    if (t + 5 < n01) i3 = srcAt(t + 5);
    // compute pair (independent shfl chains -> ILP)
    float sa = qx * blo(pka) + qy * bhi(pka);
    float sb = qx * blo(pkb) + qy * bhi(pkb);
    sa += __shfl_xor(sa, 1, 64);
    sb += __shfl_xor(sb, 1, 64);
    sa += __shfl_xor(sa, 2, 64);
    sb += __shfl_xor(sb, 2, 64);
    sa += __shfl_xor(sa, 4, 64);
    sb += __shfl_xor(sb, 4, 64);
    sa += __shfl_xor(sa, 8, 64);
    sb += __shfl_xor(sb, 8, 64);
    sa *= psa;
    sb *= psb;
    float nm = fmaxf(m, fmaxf(sa, sb));
    float c = __expf(m - nm);
    float wa = __expf(sa - nm), wb = __expf(sb - nm);
    den = den * c + wa + wb;
    ax = ax * c + wa * blo(pva) + wb * blo(pvb);
    ay = ay * c + wa * bhi(pva) + wb * bhi(pvb);
    m = nm;
  }
  if (t < n01) {  // odd tail (rows already in ka/va)
    float ps = (t < n0) ? ps0 : ps1;
    float s = qx * blo(ka) + qy * bhi(ka);
    s += __shfl_xor(s, 1, 64);
    s += __shfl_xor(s, 2, 64);
    s += __shfl_xor(s, 4, 64);
    s += __shfl_xor(s, 8, 64);
    s *= ps;
    float nm = fmaxf(m, s);
    float c = __expf(m - nm);
    float w = __expf(s - nm);
    den = den * c + w;
    ax = ax * c + w * blo(va);
    ay = ay * c + w * bhi(va);
  }
  float inv = 1.f / (den + 1e-16f);
  ax *= inv;
  ay *= inv;
  // W/O dst: M transform (raw-v aggregated; apply per-dst once)
  if (et23 >= 0) {
    const float* Mm = Ml + ((size_t)et23 * H + q) * D * D;
    int base = lane & 48;
    float o0 = 0.f, o1 = 0.f;
    #pragma unroll
    for (int j = 0; j < 16; j++) {
      float s0 = __shfl(ax, base + j, 64);
      float s1 = __shfl(ay, base + j, 64);
      float2 m0 = *(const float2*)&Mm[(2 * j) * 32 + 2 * p];
      float2 m1 = *(const float2*)&Mm[(2 * j + 1) * 32 + 2 * p];
      o0 += s0 * m0.x + s1 * m1.x;
      o1 += s0 * m0.y + s1 * m1.y;
    }
    ax = o0; ay = o1;
  }
  unsigned ov = (unsigned)f2bf(gelu_exact(ax)) |
                ((unsigned)f2bf(gelu_exact(ay)) << 16);
  *(unsigned*)(out + (size_t)dl * LDK + HID + lane * 2) = ov;
}

__global__ __launch_bounds__(256) void head_kernel(
    const unsigned short* __restrict__ xs0, const float* __restrict__ w_head,
    const float* __restrict__ b_head, const float* __restrict__ basep,
    float* __restrict__ out, int Nrows) {
  int wid = (blockIdx.x * 256 + threadIdx.x) >> 6;
  int lane = threadIdx.x & 63;
  if (wid >= Nrows) return;
  size_t base = (size_t)wid * HID;
  float d = bf2f(xs0[base + lane]) * w_head[lane] +
            bf2f(xs0[base + 64 + lane]) * w_head[64 + lane];
  #pragma unroll
  for (int m = 1; m < 64; m <<= 1) d += __shfl_xor(d, m, 64);
  if (lane == 0) out[wid] = basep[0] + b_head[0] + d;
}

}  // namespace

extern "C" void kernel_launch(void* const* d_in, const int* in_sizes, int n_in,
                              void* d_out, int out_size, void* d_ws,
                              size_t ws_size, hipStream_t stream) {
  const float* x_a = (const float*)d_in[0];
  const float* x_w = (const float*)d_in[1];
  const float* x_o = (const float*)d_in[2];
  const float* W_in = (const float*)d_in[3];
  const float* b_in = (const float*)d_in[4];
  const float* W_kqv = (const float*)d_in[5];
  const float* b_kqv = (const float*)d_in[6];
  const float* a_rel = (const float*)d_in[7];
  const float* m_rel = (const float*)d_in[8];
  const float* p_rel = (const float*)d_in[9];
  const float* skip_p = (const float*)d_in[10];
  const float* W_o = (const float*)d_in[11];
  const float* b_o = (const float*)d_in[12];
  const float* ln_g = (const float*)d_in[13];
  const float* ln_b = (const float*)d_in[14];
  const float* w_head = (const float*)d_in[15];
  const float* b_head = (const float*)d_in[16];
  const float* basep = (const float*)d_in[17];
  const int* srcs[4] = {(const int*)d_in[18], (const int*)d_in[20],
                        (const int*)d_in[22], (const int*)d_in[24]};
  const int* dsts[4] = {(const int*)d_in[19], (const int*)d_in[21],
                        (const int*)d_in[23], (const int*)d_in[25]};

  // ---- workspace layout (~186 MB) ----
  const size_t SZ_XS = (size_t)NTOT * HID * 2;
  const size_t SZ_KQV = (size_t)NTOT * LDK * 2;
  const size_t SZ_WINT = (size_t)3 * 128 * 64 * 2;
  const size_t SZ_WK0T = (size_t)2 * 384 * 128 * 2;
  const size_t SZ_WOT = (size_t)6 * 128 * 128 * 2;
  const size_t SZ_WET = (size_t)2 * 2 * 384 * 128 * 2;  // both layers
  const size_t SZ_BE = ((size_t)2 * 2 * 384 * 4 + 63) & ~63ull;
  const size_t SZ_SD = (size_t)4 * E * 4;
  const size_t SZ_DESC = (size_t)NTOT * 16;
  const int CNT_TOT = 2 * NA + NW + NO;
  const int RP_TOT = 2 * (NA + 1) + (NW + 1) + (NO + 1);
  const size_t SZ_RP = ((size_t)RP_TOT * 4 + 63) & ~63ull;
  const size_t SZ_CE = (size_t)4 * E * 4;
  const size_t SZ_CU = ((size_t)CNT_TOT * 4 + 63) & ~63ull;
  const size_t SZ_BS = 4 * 512 * 4;
  const size_t need = SZ_XS + SZ_KQV + SZ_WINT + SZ_WK0T + SZ_WOT + SZ_WET +
                      SZ_BE + SZ_SD + SZ_DESC + SZ_RP + SZ_CE + 2 * SZ_CU +
                      SZ_BS;
  if (ws_size < need) return;

  char* p = (char*)d_ws;
  unsigned short* xs = (unsigned short*)p;    p += SZ_XS;
  unsigned short* kqvB = (unsigned short*)p;  p += SZ_KQV;
  unsigned short* WinT = (unsigned short*)p;  p += SZ_WINT;
  unsigned short* Wk0T = (unsigned short*)p;  p += SZ_WK0T;
  unsigned short* WoT = (unsigned short*)p;   p += SZ_WOT;
  unsigned short* WeT = (unsigned short*)p;   p += SZ_WET;
  float* beB = (float*)p;                     p += SZ_BE;
  int* srcOf = (int*)p;                       p += SZ_SD;
  int4* descB = (int4*)p;                     p += SZ_DESC;
  int* rpAll = (int*)p;                       p += SZ_RP;
  int* ceAll = (int*)p;                       p += SZ_CE;
  int* cursor = (int*)p;                      p += SZ_CU;
  int* cnt = (int*)p;                         p += SZ_CU;
  int* bsum = (int*)p;

  const int CNTT = 2 * NA + NW + NO;
  const int e4b = (4 * E + 255) / 256;
  const int nb0 = (NA + 63) / 64, nb01 = nb0 + (NW + 63) / 64;
  const int nbTot = nb01 + (NO + 63) / 64;
  const int nbA = (NA + 255) / 256, nbW = (NW + 255) / 256,
            nbO = (NO + 255) / 256;

  // ---- CSR build (once) ----
  hipMemsetAsync(cnt, 0, (size_t)CNTT * 4, stream);
  csr_hist4<<<e4b, 256, 0, stream>>>(dsts[0], dsts[1], dsts[2], dsts[3], cnt);
  scan_block_all<<<2 * nbA + nbW + nbO, 256, 0, stream>>>(cnt, rpAll, bsum);
  scan_bsums_all<<<4, 256, 0, stream>>>(bsum);
  csr_finalize4<<<(CNTT + 255) / 256, 256, 0, stream>>>(rpAll, bsum, cursor);
  csr_scatter4<<<e4b, 256, 0, stream>>>(dsts[0], dsts[1], dsts[2], dsts[3],
                                        cursor, ceAll);
  csr_sort4<<<(CNTT + 255) / 256, 256, 0, stream>>>(rpAll, ceAll);
  build_sd<<<e4b, 256, 0, stream>>>(ceAll, srcs[0], srcs[1], srcs[2], srcs[3],
                                    srcOf);
  build_desc<<<(NTOT + 255) / 256, 256, 0, stream>>>(rpAll, descB);

  // ---- weight prep (incl. both-layer folds) + input projection ----
  prep_weights<<<(3 * 128 * 64 + 2 * 384 * 128 + 6 * 128 * 128 + 255) / 256,
                 256, 0, stream>>>(W_in, W_kqv, W_o, WinT, Wk0T, WoT);
  fold_weights2<<<dim3((2 * 128 * 384 + 2 * 384 + 255) / 256, 2), 256, 0,
                  stream>>>(W_kqv, b_kqv, a_rel, m_rel, WeT, beB);
  in_fused<<<nbTot, 256, 0, stream>>>(x_a, x_w, x_o, WinT, b_in, xs, nb0, nb01);

  const size_t DD = (size_t)H * D * D;
  for (int l = 0; l < 2; l++) {
    const float* Ml = m_rel + (size_t)l * 4 * DD;
    const float* Pl = p_rel + (size_t)l * 4 * H;
    const float* bl = b_kqv + (size_t)l * 3 * LDK;
    kqv_fused<<<dim3(nbTot, 3), 256, 0, stream>>>(
        xs, Wk0T + (size_t)l * 384 * 128, bl,
        WeT + (size_t)l * 2 * 384 * 128, beB + (size_t)l * 2 * 384, kqvB, nb0,
        nb01);
    attn_fused<<<(NTOT + 3) / 4, 256, 0, stream>>>(kqvB, descB, srcOf, Pl, Ml,
                                                   kqvB);
    wo_ln_fused<<<nbTot, 256, 0, stream>>>(
        kqvB, WoT + (size_t)l * 3 * 128 * 128, b_o + (size_t)l * 3 * HID, xs,
        skip_p + l * 3, ln_g + (size_t)l * 3 * HID, ln_b + (size_t)l * 3 * HID,
        nb0, nb01);
  }
  head_kernel<<<(NA + 3) / 4, 256, 0, stream>>>(xs, w_head, b_head, basep,
                                                (float*)d_out, NA);
}

// Round 21
// 668.376 us; speedup vs baseline: 1.1492x; 1.0530x over previous
//
#include <hip/hip_runtime.h>
#include <cstddef>
#include <cmath>

namespace {

constexpr int H = 4, D = 32, HID = 128;
constexpr int NA = 100000, NW = 20000, NO = 50000;
constexpr int NTOT = NA + NW + NO;
constexpr int E = 150000;
constexpr float SCALE = 0.17677669529663687f;  // 1/sqrt(32)
constexpr int LDK = 3 * HID;  // kqv row stride (384)

typedef __attribute__((ext_vector_type(8))) short short8v;
typedef __attribute__((ext_vector_type(4))) float f32x4;

__device__ __forceinline__ float gelu_exact(float x) {
  return 0.5f * x * (1.f + erff(x * 0.7071067811865475f));
}
__device__ __forceinline__ unsigned short f2bf(float f) {  // RNE
  unsigned u = __float_as_uint(f);
  return (unsigned short)((u + 0x7FFF + ((u >> 16) & 1)) >> 16);
}
__device__ __forceinline__ float bf2f(unsigned short s) {
  return __uint_as_float(((unsigned)s) << 16);
}
__device__ __forceinline__ float blo(unsigned w) {
  return __uint_as_float(w << 16);
}
__device__ __forceinline__ float bhi(unsigned w) {
  return __uint_as_float(w & 0xFFFF0000u);
}

__device__ __forceinline__ int btype(int bx, int nb0, int nb01) {
  return bx < nb0 ? 0 : (bx < nb01 ? 1 : 2);
}

// ---------------- swizzled BK=64 MFMA GEMM body ----------------
template <int KSTEPS, bool A_FP32>
__device__ __forceinline__ void gemm_body(
    const void* __restrict__ Av, int lda, const unsigned short* __restrict__ BT,
    int ldb, f32x4* acc, int M, int bm) {
  __shared__ unsigned short As[64 * 64];
  __shared__ unsigned short Bs[128 * 64];
  const int tid = threadIdx.x;
  const int wv = tid >> 6, l = tid & 63;
  for (int ks = 0; ks < KSTEPS; ks++) {
    const int kk = ks * 64;
    #pragma unroll
    for (int p = 0; p < 2; p++) {
      int idx = tid + p * 256;
      int r = idx >> 3, c = idx & 7;
      int gr = bm + r;
      unsigned short tmp[8] = {0, 0, 0, 0, 0, 0, 0, 0};
      if (gr < M) {
        if (A_FP32) {
          const float* src = (const float*)Av + (size_t)gr * lda + kk + c * 8;
          float4 f0 = *(const float4*)src;
          float4 f1 = *(const float4*)(src + 4);
          tmp[0] = f2bf(f0.x); tmp[1] = f2bf(f0.y);
          tmp[2] = f2bf(f0.z); tmp[3] = f2bf(f0.w);
          tmp[4] = f2bf(f1.x); tmp[5] = f2bf(f1.y);
          tmp[6] = f2bf(f1.z); tmp[7] = f2bf(f1.w);
        } else {
          *(uint4*)tmp = *(const uint4*)((const unsigned short*)Av +
                                         (size_t)gr * lda + kk + c * 8);
        }
      }
      *(uint4*)&As[r * 64 + ((c ^ (r & 7)) * 8)] = *(const uint4*)tmp;
    }
    #pragma unroll
    for (int p = 0; p < 4; p++) {
      int idx = tid + p * 256;
      int r = idx >> 3, c = idx & 7;
      uint4 v = *(const uint4*)(BT + (size_t)r * ldb + kk + c * 8);
      *(uint4*)&Bs[r * 64 + ((c ^ (r & 7)) * 8)] = v;
    }
    __syncthreads();
    const int arow = wv * 16 + (l & 15);
    #pragma unroll
    for (int ksub = 0; ksub < 2; ksub++) {
      int ch = ksub * 4 + (l >> 4);
      short8v af = *(const short8v*)&As[arow * 64 + ((ch ^ (arow & 7)) * 8)];
      #pragma unroll
      for (int n = 0; n < 8; n++) {
        int brow = n * 16 + (l & 15);
        short8v bf =
            *(const short8v*)&Bs[brow * 64 + ((ch ^ (brow & 7)) * 8)];
        acc[n] =
            __builtin_amdgcn_mfma_f32_16x16x32_bf16(af, bf, acc[n], 0, 0, 0);
      }
    }
    __syncthreads();
  }
}

// ---------------- weight prep: bf16 transposed copies ----------------
__global__ __launch_bounds__(256) void prep_weights(
    const float* __restrict__ W_in, const float* __restrict__ W_kqv,
    const float* __restrict__ W_o, unsigned short* __restrict__ WinT,
    unsigned short* __restrict__ Wk0T, unsigned short* __restrict__ WoT) {
  int idx = blockIdx.x * 256 + threadIdx.x;
  const int N1 = 3 * 128 * 64, N2 = 2 * 384 * 128, N3 = 6 * 128 * 128;
  if (idx < N1) {
    int t = idx / 8192, rem = idx - t * 8192;
    int n = rem >> 6, k = rem & 63;
    WinT[idx] = f2bf(W_in[(size_t)t * 64 * 128 + (size_t)k * 128 + n]);
  } else if (idx < N1 + N2) {
    int r = idx - N1;
    int lyr = r / (384 * 128), rem = r - lyr * (384 * 128);
    int n = rem >> 7, k = rem & 127;
    Wk0T[r] = f2bf(W_kqv[(size_t)lyr * 3 * 128 * 384 + (size_t)k * 384 + n]);
  } else if (idx < N1 + N2 + N3) {
    int r = idx - N1 - N2;
    int lt = r / (128 * 128), rem = r - lt * (128 * 128);
    int n = rem >> 7, k = rem & 127;
    WoT[r] = f2bf(W_o[(size_t)lt * 128 * 128 + (size_t)k * 128 + n]);
  }
}

// ---------------- weight folding (BOTH layers; y = layer) ----------------
__global__ __launch_bounds__(256) void fold_weights2(
    const float* __restrict__ W_kqv, const float* __restrict__ b_kqv,
    const float* __restrict__ a_rel, const float* __restrict__ m_rel,
    unsigned short* __restrict__ WeT, float* __restrict__ be) {
  const int lyr = blockIdx.y;
  const size_t DD = (size_t)H * D * D;
  const float* Wl = W_kqv + (size_t)lyr * 3 * HID * LDK;
  const float* bl = b_kqv + (size_t)lyr * 3 * LDK;
  const float* Al = a_rel + (size_t)lyr * 4 * DD;
  const float* Ml = m_rel + (size_t)lyr * 4 * DD;
  unsigned short* WeTl = WeT + (size_t)lyr * 2 * 384 * 128;
  float* bel = be + (size_t)lyr * 2 * 384;
  int idx = blockIdx.x * 256 + threadIdx.x;
  const int NW_ = 2 * 128 * 384;
  if (idx < NW_) {
    int tt = idx / (128 * 384);
    int rem = idx - tt * (128 * 384);
    int r = rem / 384, c = rem - r * 384;
    int slice = c >> 7, h = (c >> 5) & 3, j = c & 31;
    const float* Wsrc = Wl + (size_t)(tt + 1) * 128 * 384 + (size_t)r * 384;
    float acc = 0.f;
    if (slice == 0) {
      const float* A = Al + ((size_t)tt * H + h) * D * D;
      for (int d = 0; d < 32; d++) acc += Wsrc[h * 32 + d] * A[d * 32 + j];
    } else if (slice == 1) {
      const float* A = Al + ((size_t)(2 + tt) * H + h) * D * D;
      for (int e = 0; e < 32; e++)
        acc += Wsrc[128 + h * 32 + e] * A[j * 32 + e];
    } else {
      const float* Mm = Ml + ((size_t)tt * H + h) * D * D;
      for (int d = 0; d < 32; d++)
        acc += Wsrc[256 + h * 32 + d] * Mm[d * 32 + j];
    }
    WeTl[(size_t)tt * 384 * 128 + (size_t)c * 128 + r] = f2bf(acc);
  } else if (idx < NW_ + 2 * 384) {
    int rem = idx - NW_;
    int tt = rem / 384, c = rem - tt * 384;
    int slice = c >> 7, h = (c >> 5) & 3, j = c & 31;
    const float* bsrc = bl + (size_t)(tt + 1) * 384;
    float acc = 0.f;
    if (slice == 0) {
      const float* A = Al + ((size_t)tt * H + h) * D * D;
      for (int d = 0; d < 32; d++) acc += bsrc[h * 32 + d] * A[d * 32 + j];
    } else if (slice == 1) {
      const float* A = Al + ((size_t)(2 + tt) * H + h) * D * D;
      for (int e = 0; e < 32; e++)
        acc += bsrc[128 + h * 32 + e] * A[j * 32 + e];
    } else {
      const float* Mm = Ml + ((size_t)tt * H + h) * D * D;
      for (int d = 0; d < 32; d++)
        acc += bsrc[256 + h * 32 + d] * Mm[d * 32 + j];
    }
    bel[rem] = acc;
  }
}

// input proj: xs = relu(x @ W_in[t] + b_in[t])
__global__ __launch_bounds__(256) void in_fused(
    const float* __restrict__ xa, const float* __restrict__ xw,
    const float* __restrict__ xo, const unsigned short* __restrict__ WinT,
    const float* __restrict__ b_in, unsigned short* __restrict__ xs, int nb0,
    int nb01) {
  int t = btype(blockIdx.x, nb0, nb01);
  int base = t == 0 ? 0 : (t == 1 ? nb0 : nb01);
  int M = t == 0 ? NA : (t == 1 ? NW : NO);
  int off = t == 0 ? 0 : (t == 1 ? NA : NA + NW);
  const float* A = t == 0 ? xa : (t == 1 ? xw : xo);
  const int bm = (blockIdx.x - base) * 64;
  f32x4 acc[8] = {};
  gemm_body<1, true>(A, 64, WinT + (size_t)t * 128 * 64, 64, acc, M, bm);
  const int l = threadIdx.x & 63, wv = threadIdx.x >> 6;
  const float* bias = b_in + t * HID;
  unsigned short* C = xs + (size_t)off * HID;
  #pragma unroll
  for (int n = 0; n < 8; n++) {
    int col = n * 16 + (l & 15);
    float bb = bias[col];
    #pragma unroll
    for (int j = 0; j < 4; j++) {
      int row = bm + wv * 16 + (l >> 4) * 4 + j;
      if (row < M) C[(size_t)row * HID + col] = f2bf(fmaxf(acc[n][j] + bb, 0.f));
    }
  }
}

// kqv proj: full-width 64x384 per block; A staged once (full K in LDS),
// 3 internal 128-col tiles. t=0 raw Wk0T; t=1,2 folded WeT.
__global__ __launch_bounds__(256) void kqv_fused(
    const unsigned short* __restrict__ xs, const unsigned short* __restrict__ Wk0Tl,
    const float* __restrict__ b0, const unsigned short* __restrict__ WeT,
    const float* __restrict__ be, unsigned short* __restrict__ kqvB, int nb0,
    int nb01) {
  __shared__ unsigned short As[64 * 128];   // 16 KB, full K
  __shared__ unsigned short Bs[128 * 128];  // 32 KB per col-tile
  int t = btype(blockIdx.x, nb0, nb01);
  int base = t == 0 ? 0 : (t == 1 ? nb0 : nb01);
  int M = t == 0 ? NA : (t == 1 ? NW : NO);
  int off = t == 0 ? 0 : (t == 1 ? NA : NA + NW);
  const unsigned short* BT =
      (t == 0 ? Wk0Tl : WeT + (size_t)(t - 1) * 384 * 128);
  const float* bias = t == 0 ? b0 : be + (size_t)(t - 1) * 384;
  const int bm = (blockIdx.x - base) * 64;
  const int tid = threadIdx.x;
  const int wv = tid >> 6, l = tid & 63;
  // stage A once: 64 rows x 16 chunks (16B), XOR-16 swizzle
  // NOTE: xs rows are GLOBAL (off + local) — this was the R20 bug.
  #pragma unroll
  for (int p = 0; p < 4; p++) {
    int idx = tid + p * 256;
    int r = idx >> 4, c = idx & 15;
    int gr = bm + r;
    uint4 v = {0, 0, 0, 0};
    if (gr < M)
      v = *(const uint4*)(xs + (size_t)(off + gr) * HID + c * 8);
    *(uint4*)&As[r * 128 + ((c ^ (r & 15)) * 8)] = v;
  }
  const int arow = wv * 16 + (l & 15);
  unsigned short* C = kqvB + (size_t)off * LDK;
  for (int bn = 0; bn < 384; bn += 128) {
    if (bn) __syncthreads();  // protect Bs before restage
    #pragma unroll
    for (int p = 0; p < 8; p++) {
      int idx = tid + p * 256;
      int r = idx >> 4, c = idx & 15;
      uint4 v = *(const uint4*)(BT + (size_t)(bn + r) * 128 + c * 8);
      *(uint4*)&Bs[r * 128 + ((c ^ (r & 15)) * 8)] = v;
    }
    __syncthreads();
    f32x4 acc[8] = {};
    #pragma unroll
    for (int ks = 0; ks < 4; ks++) {
      int ch = ks * 4 + (l >> 4);
      short8v af = *(const short8v*)&As[arow * 128 + ((ch ^ (arow & 15)) * 8)];
      #pragma unroll
      for (int n = 0; n < 8; n++) {
        int brow = n * 16 + (l & 15);
        short8v bf =
            *(const short8v*)&Bs[brow * 128 + ((ch ^ (brow & 15)) * 8)];
        acc[n] =
            __builtin_amdgcn_mfma_f32_16x16x32_bf16(af, bf, acc[n], 0, 0, 0);
      }
    }
    #pragma unroll
    for (int n = 0; n < 8; n++) {
      int col = bn + n * 16 + (l & 15);
      float bb = bias[col];
      #pragma unroll
      for (int j = 0; j < 4; j++) {
        int row = bm + wv * 16 + (l >> 4) * 4 + j;
        if (row < M) C[(size_t)row * LDK + col] = f2bf(acc[n][j] + bb);
      }
    }
  }
}

// fused: xs = relu(LN( g*(agg_gelu @ W_o + b_o) + (1-g)*xs ))
__global__ __launch_bounds__(256) void wo_ln_fused(
    const unsigned short* __restrict__ kqvB, const unsigned short* __restrict__ WoTl,
    const float* __restrict__ bl, unsigned short* __restrict__ xs,
    const float* __restrict__ skipl, const float* __restrict__ gll,
    const float* __restrict__ bll, int nb0, int nb01) {
  int t = btype(blockIdx.x, nb0, nb01);
  int base = t == 0 ? 0 : (t == 1 ? nb0 : nb01);
  int M = t == 0 ? NA : (t == 1 ? NW : NO);
  int off = t == 0 ? 0 : (t == 1 ? NA : NA + NW);
  const int bm = (blockIdx.x - base) * 64;
  f32x4 acc[8] = {};
  gemm_body<2, false>(kqvB + (size_t)off * LDK + HID, LDK,
                      WoTl + (size_t)t * 128 * 128, 128, acc, M, bm);
  const int l = threadIdx.x & 63, wv = threadIdx.x >> 6;
  const float* bias = bl + t * HID;
  const float* gln = gll + t * HID;
  const float* bln = bll + t * HID;
  unsigned short* xsT = xs + (size_t)off * HID;
  const float g = 1.f / (1.f + expf(-skipl[t]));
  float bb[8], gl8[8], bl8[8];
  #pragma unroll
  for (int n = 0; n < 8; n++) {
    int col = n * 16 + (l & 15);
    bb[n] = bias[col];
    gl8[n] = gln[col];
    bl8[n] = bln[col];
  }
  #pragma unroll
  for (int j = 0; j < 4; j++) {
    int row = bm + wv * 16 + (l >> 4) * 4 + j;
    bool ok = row < M;
    float vv[8], sum = 0.f, sq = 0.f;
    #pragma unroll
    for (int n = 0; n < 8; n++) {
      int col = n * 16 + (l & 15);
      float xo = ok ? bf2f(xsT[(size_t)row * HID + col]) : 0.f;
      float val = g * (acc[n][j] + bb[n]) + (1.f - g) * xo;
      vv[n] = val;
      sum += val;
      sq += val * val;
    }
    #pragma unroll
    for (int m = 1; m < 16; m <<= 1) {
      sum += __shfl_xor(sum, m, 64);
      sq += __shfl_xor(sq, m, 64);
    }
    float mu = sum * (1.f / 128.f);
    float var = sq * (1.f / 128.f) - mu * mu;
    float r = rsqrtf(var + 1e-5f);
    if (ok) {
      #pragma unroll
      for (int n = 0; n < 8; n++) {
        float y = fmaxf((vv[n] - mu) * r * gl8[n] + bl8[n], 0.f);
        xsT[(size_t)row * HID + n * 16 + (l & 15)] = f2bf(y);
      }
    }
  }
}

// ---------------- CSR build (deterministic, 4 ets fused) ----------------
__global__ __launch_bounds__(256) void csr_hist4(
    const int* __restrict__ d0, const int* __restrict__ d1,
    const int* __restrict__ d2, const int* __restrict__ d3,
    int* __restrict__ cnt) {
  int t = blockIdx.x * 256 + threadIdx.x;
  if (t >= 4 * E) return;
  int et = t / E, e = t - et * E;
  const int* dp = et == 0 ? d0 : et == 1 ? d1 : et == 2 ? d2 : d3;
  int base = et == 0 ? 0 : et == 1 ? NA : et == 2 ? 2 * NA : 2 * NA + NW;
  atomicAdd(&cnt[base + dp[e]], 1);
}

// fused per-256-block scan over all 4 et regions (grid partitioned by et)
__global__ __launch_bounds__(256) void scan_block_all(
    const int* __restrict__ cnt, int* __restrict__ rpAll,
    int* __restrict__ bsum) {
  const int nbA = (NA + 255) / 256, nbW = (NW + 255) / 256,
            nbO = (NO + 255) / 256;
  int bx = blockIdx.x;
  int et, bbase, cbase, rpo, n;
  if (bx < nbA) { et = 0; bbase = 0; cbase = 0; rpo = 0; n = NA; }
  else if (bx < 2 * nbA) { et = 1; bbase = nbA; cbase = NA; rpo = NA + 1; n = NA; }
  else if (bx < 2 * nbA + nbW) {
    et = 2; bbase = 2 * nbA; cbase = 2 * NA; rpo = 2 * (NA + 1); n = NW;
  } else {
    et = 3; bbase = 2 * nbA + nbW; cbase = 2 * NA + NW;
    rpo = 2 * (NA + 1) + (NW + 1); n = NO;
  }
  int lb = bx - bbase;
  __shared__ int tmp[256];
  int i = lb * 256 + threadIdx.x;
  int v = (i < n) ? cnt[cbase + i] : 0;
  tmp[threadIdx.x] = v;
  __syncthreads();
  int acc = v;
  for (int off = 1; off < 256; off <<= 1) {
    int other = (threadIdx.x >= off) ? tmp[threadIdx.x - off] : 0;
    __syncthreads();
    acc += other;
    tmp[threadIdx.x] = acc;
    __syncthreads();
  }
  if (i < n) rpAll[rpo + i] = acc - v;
  if (threadIdx.x == 255) bsum[et * 512 + lb] = acc;
}

// fused bsum scans: 4 blocks, one per et
__global__ __launch_bounds__(256) void scan_bsums_all(int* __restrict__ bsum) {
  int et = blockIdx.x;
  int nb = et < 2 ? (NA + 255) / 256 : (et == 2 ? (NW + 255) / 256
                                                : (NO + 255) / 256);
  int* bs = bsum + et * 512;
  __shared__ int tmp[256];
  __shared__ int carry;
  if (threadIdx.x == 0) carry = 0;
  __syncthreads();
  for (int start = 0; start < nb; start += 256) {
    int i = start + threadIdx.x;
    int v = (i < nb) ? bs[i] : 0;
    tmp[threadIdx.x] = v;
    __syncthreads();
    int acc = v;
    for (int off = 1; off < 256; off <<= 1) {
      int other = (threadIdx.x >= off) ? tmp[threadIdx.x - off] : 0;
      __syncthreads();
      acc += other;
      tmp[threadIdx.x] = acc;
      __syncthreads();
    }
    int c = carry;
    if (i < nb) bs[i] = c + acc - v;
    __syncthreads();
    if (threadIdx.x == 255) carry = c + acc;
    __syncthreads();
  }
}

__device__ __forceinline__ void et_of_node(int i, int& et, int& base, int& nd,
                                           int& rpo) {
  if (i < NA) { et = 0; base = 0; nd = NA; rpo = 0; }
  else if (i < 2 * NA) { et = 1; base = NA; nd = NA; rpo = NA + 1; }
  else if (i < 2 * NA + NW) { et = 2; base = 2 * NA; nd = NW; rpo = 2 * (NA + 1); }
  else { et = 3; base = 2 * NA + NW; nd = NO; rpo = 2 * (NA + 1) + NW + 1; }
}

__global__ __launch_bounds__(256) void csr_finalize4(
    int* __restrict__ rpAll, const int* __restrict__ bsum,
    int* __restrict__ cursor) {
  int i = blockIdx.x * 256 + threadIdx.x;
  if (i >= 2 * NA + NW + NO) return;
  int et, base, nd, rpo;
  et_of_node(i, et, base, nd, rpo);
  int local = i - base;
  int v = rpAll[rpo + local] + bsum[et * 512 + (local >> 8)];
  rpAll[rpo + local] = v;
  cursor[base + local] = v;
  if (local == 0) rpAll[rpo + nd] = E;
}

__global__ __launch_bounds__(256) void csr_scatter4(
    const int* __restrict__ d0, const int* __restrict__ d1,
    const int* __restrict__ d2, const int* __restrict__ d3,
    int* __restrict__ cursor, int* __restrict__ ceAll) {
  int t = blockIdx.x * 256 + threadIdx.x;
  if (t >= 4 * E) return;
  int et = t / E, e = t - et * E;
  const int* dp = et == 0 ? d0 : et == 1 ? d1 : et == 2 ? d2 : d3;
  int base = et == 0 ? 0 : et == 1 ? NA : et == 2 ? 2 * NA : 2 * NA + NW;
  int slot = atomicAdd(&cursor[base + dp[e]], 1);
  ceAll[(size_t)et * E + slot] = e;
}

__global__ __launch_bounds__(256) void csr_sort4(const int* __restrict__ rpAll,
                                                 int* __restrict__ ceAll) {
  int i = blockIdx.x * 256 + threadIdx.x;
  if (i >= 2 * NA + NW + NO) return;
  int et, base, nd, rpo;
  et_of_node(i, et, base, nd, rpo);
  int local = i - base;
  int b = rpAll[rpo + local], e = rpAll[rpo + local + 1];
  int* ce = ceAll + (size_t)et * E;
  for (int k = b + 1; k < e; k++) {
    int key = ce[k];
    int j = k - 1;
    while (j >= b && ce[j] > key) { ce[j + 1] = ce[j]; j--; }
    ce[j + 1] = key;
  }
}

// slot-ordered GLOBAL src node ids
__global__ __launch_bounds__(256) void build_sd(
    const int* __restrict__ ce, const int* __restrict__ s0,
    const int* __restrict__ s1, const int* __restrict__ s2,
    const int* __restrict__ s3, int* __restrict__ srcOf) {
  int t = blockIdx.x * 256 + threadIdx.x;
  if (t >= 4 * E) return;
  int et = t / E;
  int e = ce[t];
  const int* sp = et == 0 ? s0 : et == 1 ? s1 : et == 2 ? s2 : s3;
  int sOff = et == 0 ? NA : et == 1 ? NA + NW : 0;
  srcOf[t] = sOff + sp[e];
}

// packed per-dst edge ranges: desc[dl] = (b0, e0, b1, e1); W/O: b1=e1=0
__global__ __launch_bounds__(256) void build_desc(const int* __restrict__ rpAll,
                                                  int4* __restrict__ desc) {
  int dl = blockIdx.x * 256 + threadIdx.x;
  if (dl >= NTOT) return;
  int4 d;
  if (dl < NA) {
    d.x = rpAll[dl]; d.y = rpAll[dl + 1];
    d.z = rpAll[(NA + 1) + dl]; d.w = rpAll[(NA + 1) + dl + 1];
  } else if (dl < NA + NW) {
    int x = dl - NA;
    d.x = rpAll[2 * (NA + 1) + x]; d.y = rpAll[2 * (NA + 1) + x + 1];
    d.z = 0; d.w = 0;
  } else {
    int x = dl - NA - NW;
    d.x = rpAll[2 * (NA + 1) + (NW + 1) + x];
    d.y = rpAll[2 * (NA + 1) + (NW + 1) + x + 1];
    d.z = 0; d.w = 0;
  }
  desc[dl] = d;
}

// ---------------- fused attention (online softmax, 2-wide pipelined) ------
__global__ __launch_bounds__(256) void attn_fused(
    const unsigned short* __restrict__ kqv, const int4* __restrict__ desc,
    const int* __restrict__ srcOf, const float* __restrict__ Pl,
    const float* __restrict__ Ml, unsigned short* __restrict__ out) {
  int dl = (blockIdx.x * 256 + threadIdx.x) >> 6;
  int lane = threadIdx.x & 63;
  if (dl >= NTOT) return;
  int q = lane >> 4, p = lane & 15;
  int4 dd = desc[dl];
  int b0 = dd.x, e0 = dd.y, b1 = dd.z, e1 = dd.w;
  int et23 = -1;
  const int* so0;
  const int* so1 = srcOf;
  float ps0, ps1 = 0.f;
  if (dl < NA) {
    so0 = srcOf; so1 = srcOf + E;
    ps0 = Pl[q] * SCALE; ps1 = Pl[H + q] * SCALE;
  } else if (dl < NA + NW) {
    so0 = srcOf + 2 * (size_t)E;
    ps0 = Pl[2 * H + q] * SCALE;
    et23 = 2;
  } else {
    so0 = srcOf + 3 * (size_t)E;
    ps0 = Pl[3 * H + q] * SCALE;
    et23 = 3;
  }
  const int n0 = e0 - b0;
  const int n01 = n0 + (e1 - b1);
  auto srcAt = [&](int t) -> int {
    return (t < n0) ? so0[b0 + t] : so1[b1 + (t - n0)];
  };
  unsigned qv = *(const unsigned*)(kqv + (size_t)dl * LDK + HID + lane * 2);
  float qx = blo(qv), qy = bhi(qv);
  const int lo2 = lane * 2;

  float m = -INFINITY, den = 0.f, ax = 0.f, ay = 0.f;
  unsigned ka = 0, va = 0, kb = 0, vb = 0;
  int i2 = 0, i3 = 0;
  if (n01 > 0) {
    const unsigned short* r = kqv + (size_t)srcAt(0) * LDK;
    ka = *(const unsigned*)(r + lo2);
    va = *(const unsigned*)(r + 2 * HID + lo2);
  }
  if (n01 > 1) {
    const unsigned short* r = kqv + (size_t)srcAt(1) * LDK;
    kb = *(const unsigned*)(r + lo2);
    vb = *(const unsigned*)(r + 2 * HID + lo2);
  }
  if (n01 > 2) i2 = srcAt(2);
  if (n01 > 3) i3 = srcAt(3);
  int t = 0;
  for (; t + 1 < n01; t += 2) {
    unsigned pka = ka, pva = va, pkb = kb, pvb = vb;
    float psa = (t < n0) ? ps0 : ps1;
    float psb = (t + 1 < n0) ? ps0 : ps1;
    if (t + 2 < n01) {
      const unsigned short* r = kqv + (size_t)i2 * LDK;
      ka = *(const unsigned*)(r + lo2);
      va = *(const unsigned*)(r + 2 * HID + lo2);
    }
    if (t + 3 < n01) {
      const unsigned short* r = kqv + (size_t)i3 * LDK;
      kb = *(const unsigned*)(r + lo2);
      vb = *(const unsigned*)(r + 2 * HID + lo2);
    }
    if (t + 4 < n01) i2 = srcAt(t + 4);
    if (t + 5 < n01) i3 = srcAt(t + 5);
    float sa = qx * blo(pka) + qy * bhi(pka);
    float sb = qx * blo(pkb) + qy * bhi(pkb);
    sa += __shfl_xor(sa, 1, 64);
    sb += __shfl_xor(sb, 1, 64);
    sa += __shfl_xor(sa, 2, 64);
    sb += __shfl_xor(sb, 2, 64);
    sa += __shfl_xor(sa, 4, 64);
    sb += __shfl_xor(sb, 4, 64);
    sa += __shfl_xor(sa, 8, 64);
    sb += __shfl_xor(sb, 8, 64);
    sa *= psa;
    sb *= psb;
    float nm = fmaxf(m, fmaxf(sa, sb));
    float c = __expf(m - nm);
    float wa = __expf(sa - nm), wb = __expf(sb - nm);
    den = den * c + wa + wb;
    ax = ax * c + wa * blo(pva) + wb * blo(pvb);
    ay = ay * c + wa * bhi(pva) + wb * bhi(pvb);
    m = nm;
  }
  if (t < n01) {
    float ps = (t < n0) ? ps0 : ps1;
    float s = qx * blo(ka) + qy * bhi(ka);
    s += __shfl_xor(s, 1, 64);
    s += __shfl_xor(s, 2, 64);
    s += __shfl_xor(s, 4, 64);
    s += __shfl_xor(s, 8, 64);
    s *= ps;
    float nm = fmaxf(m, s);
    float c = __expf(m - nm);
    float w = __expf(s - nm);
    den = den * c + w;
    ax = ax * c + w * blo(va);
    ay = ay * c + w * bhi(va);
  }
  float inv = 1.f / (den + 1e-16f);
  ax *= inv;
  ay *= inv;
  if (et23 >= 0) {
    const float* Mm = Ml + ((size_t)et23 * H + q) * D * D;
    int base = lane & 48;
    float o0 = 0.f, o1 = 0.f;
    #pragma unroll
    for (int j = 0; j < 16; j++) {
      float s0 = __shfl(ax, base + j, 64);
      float s1 = __shfl(ay, base + j, 64);
      float2 m0 = *(const float2*)&Mm[(2 * j) * 32 + 2 * p];
      float2 m1 = *(const float2*)&Mm[(2 * j + 1) * 32 + 2 * p];
      o0 += s0 * m0.x + s1 * m1.x;
      o1 += s0 * m0.y + s1 * m1.y;
    }
    ax = o0; ay = o1;
  }
  unsigned ov = (unsigned)f2bf(gelu_exact(ax)) |
                ((unsigned)f2bf(gelu_exact(ay)) << 16);
  *(unsigned*)(out + (size_t)dl * LDK + HID + lane * 2) = ov;
}

__global__ __launch_bounds__(256) void head_kernel(
    const unsigned short* __restrict__ xs0, const float* __restrict__ w_head,
    const float* __restrict__ b_head, const float* __restrict__ basep,
    float* __restrict__ out, int Nrows) {
  int wid = (blockIdx.x * 256 + threadIdx.x) >> 6;
  int lane = threadIdx.x & 63;
  if (wid >= Nrows) return;
  size_t base = (size_t)wid * HID;
  float d = bf2f(xs0[base + lane]) * w_head[lane] +
            bf2f(xs0[base + 64 + lane]) * w_head[64 + lane];
  #pragma unroll
  for (int m = 1; m < 64; m <<= 1) d += __shfl_xor(d, m, 64);
  if (lane == 0) out[wid] = basep[0] + b_head[0] + d;
}

}  // namespace

extern "C" void kernel_launch(void* const* d_in, const int* in_sizes, int n_in,
                              void* d_out, int out_size, void* d_ws,
                              size_t ws_size, hipStream_t stream) {
  const float* x_a = (const float*)d_in[0];
  const float* x_w = (const float*)d_in[1];
  const float* x_o = (const float*)d_in[2];
  const float* W_in = (const float*)d_in[3];
  const float* b_in = (const float*)d_in[4];
  const float* W_kqv = (const float*)d_in[5];
  const float* b_kqv = (const float*)d_in[6];
  const float* a_rel = (const float*)d_in[7];
  const float* m_rel = (const float*)d_in[8];
  const float* p_rel = (const float*)d_in[9];
  const float* skip_p = (const float*)d_in[10];
  const float* W_o = (const float*)d_in[11];
  const float* b_o = (const float*)d_in[12];
  const float* ln_g = (const float*)d_in[13];
  const float* ln_b = (const float*)d_in[14];
  const float* w_head = (const float*)d_in[15];
  const float* b_head = (const float*)d_in[16];
  const float* basep = (const float*)d_in[17];
  const int* srcs[4] = {(const int*)d_in[18], (const int*)d_in[20],
                        (const int*)d_in[22], (const int*)d_in[24]};
  const int* dsts[4] = {(const int*)d_in[19], (const int*)d_in[21],
                        (const int*)d_in[23], (const int*)d_in[25]};

  // ---- workspace layout (~186 MB) ----
  const size_t SZ_XS = (size_t)NTOT * HID * 2;
  const size_t SZ_KQV = (size_t)NTOT * LDK * 2;
  const size_t SZ_WINT = (size_t)3 * 128 * 64 * 2;
  const size_t SZ_WK0T = (size_t)2 * 384 * 128 * 2;
  const size_t SZ_WOT = (size_t)6 * 128 * 128 * 2;
  const size_t SZ_WET = (size_t)2 * 2 * 384 * 128 * 2;  // both layers
  const size_t SZ_BE = ((size_t)2 * 2 * 384 * 4 + 63) & ~63ull;
  const size_t SZ_SD = (size_t)4 * E * 4;
  const size_t SZ_DESC = (size_t)NTOT * 16;
  const int CNT_TOT = 2 * NA + NW + NO;
  const int RP_TOT = 2 * (NA + 1) + (NW + 1) + (NO + 1);
  const size_t SZ_RP = ((size_t)RP_TOT * 4 + 63) & ~63ull;
  const size_t SZ_CE = (size_t)4 * E * 4;
  const size_t SZ_CU = ((size_t)CNT_TOT * 4 + 63) & ~63ull;
  const size_t SZ_BS = 4 * 512 * 4;
  const size_t need = SZ_XS + SZ_KQV + SZ_WINT + SZ_WK0T + SZ_WOT + SZ_WET +
                      SZ_BE + SZ_SD + SZ_DESC + SZ_RP + SZ_CE + 2 * SZ_CU +
                      SZ_BS;
  if (ws_size < need) return;

  char* p = (char*)d_ws;
  unsigned short* xs = (unsigned short*)p;    p += SZ_XS;
  unsigned short* kqvB = (unsigned short*)p;  p += SZ_KQV;
  unsigned short* WinT = (unsigned short*)p;  p += SZ_WINT;
  unsigned short* Wk0T = (unsigned short*)p;  p += SZ_WK0T;
  unsigned short* WoT = (unsigned short*)p;   p += SZ_WOT;
  unsigned short* WeT = (unsigned short*)p;   p += SZ_WET;
  float* beB = (float*)p;                     p += SZ_BE;
  int* srcOf = (int*)p;                       p += SZ_SD;
  int4* descB = (int4*)p;                     p += SZ_DESC;
  int* rpAll = (int*)p;                       p += SZ_RP;
  int* ceAll = (int*)p;                       p += SZ_CE;
  int* cursor = (int*)p;                      p += SZ_CU;
  int* cnt = (int*)p;                         p += SZ_CU;
  int* bsum = (int*)p;

  const int CNTT = 2 * NA + NW + NO;
  const int e4b = (4 * E + 255) / 256;
  const int nb0 = (NA + 63) / 64, nb01 = nb0 + (NW + 63) / 64;
  const int nbTot = nb01 + (NO + 63) / 64;
  const int nbA = (NA + 255) / 256, nbW = (NW + 255) / 256,
            nbO = (NO + 255) / 256;

  // ---- CSR build (once) ----
  hipMemsetAsync(cnt, 0, (size_t)CNTT * 4, stream);
  csr_hist4<<<e4b, 256, 0, stream>>>(dsts[0], dsts[1], dsts[2], dsts[3], cnt);
  scan_block_all<<<2 * nbA + nbW + nbO, 256, 0, stream>>>(cnt, rpAll, bsum);
  scan_bsums_all<<<4, 256, 0, stream>>>(bsum);
  csr_finalize4<<<(CNTT + 255) / 256, 256, 0, stream>>>(rpAll, bsum, cursor);
  csr_scatter4<<<e4b, 256, 0, stream>>>(dsts[0], dsts[1], dsts[2], dsts[3],
                                        cursor, ceAll);
  csr_sort4<<<(CNTT + 255) / 256, 256, 0, stream>>>(rpAll, ceAll);
  build_sd<<<e4b, 256, 0, stream>>>(ceAll, srcs[0], srcs[1], srcs[2], srcs[3],
                                    srcOf);
  build_desc<<<(NTOT + 255) / 256, 256, 0, stream>>>(rpAll, descB);

  // ---- weight prep (incl. both-layer folds) + input projection ----
  prep_weights<<<(3 * 128 * 64 + 2 * 384 * 128 + 6 * 128 * 128 + 255) / 256,
                 256, 0, stream>>>(W_in, W_kqv, W_o, WinT, Wk0T, WoT);
  fold_weights2<<<dim3((2 * 128 * 384 + 2 * 384 + 255) / 256, 2), 256, 0,
                  stream>>>(W_kqv, b_kqv, a_rel, m_rel, WeT, beB);
  in_fused<<<nbTot, 256, 0, stream>>>(x_a, x_w, x_o, WinT, b_in, xs, nb0, nb01);

  const size_t DD = (size_t)H * D * D;
  for (int l = 0; l < 2; l++) {
    const float* Ml = m_rel + (size_t)l * 4 * DD;
    const float* Pl = p_rel + (size_t)l * 4 * H;
    const float* bl = b_kqv + (size_t)l * 3 * LDK;
    kqv_fused<<<nbTot, 256, 0, stream>>>(
        xs, Wk0T + (size_t)l * 384 * 128, bl,
        WeT + (size_t)l * 2 * 384 * 128, beB + (size_t)l * 2 * 384, kqvB, nb0,
        nb01);
    attn_fused<<<(NTOT + 3) / 4, 256, 0, stream>>>(kqvB, descB, srcOf, Pl, Ml,
                                                   kqvB);
    wo_ln_fused<<<nbTot, 256, 0, stream>>>(
        kqvB, WoT + (size_t)l * 3 * 128 * 128, b_o + (size_t)l * 3 * HID, xs,
        skip_p + l * 3, ln_g + (size_t)l * 3 * HID, ln_b + (size_t)l * 3 * HID,
        nb0, nb01);
  }
  head_kernel<<<(NA + 3) / 4, 256, 0, stream>>>(xs, w_head, b_head, basep,
                                                (float*)d_out, NA);
}

// Round 22
// 660.227 us; speedup vs baseline: 1.1634x; 1.0123x over previous
//
#include <hip/hip_runtime.h>
#include <cstddef>
#include <cmath>

namespace {

constexpr int H = 4, D = 32, HID = 128;
constexpr int NA = 100000, NW = 20000, NO = 50000;
constexpr int NTOT = NA + NW + NO;
constexpr int E = 150000;
constexpr float SCALE = 0.17677669529663687f;  // 1/sqrt(32)
constexpr int LDK = 3 * HID;  // kqv row stride (384)

typedef __attribute__((ext_vector_type(8))) short short8v;
typedef __attribute__((ext_vector_type(4))) float f32x4;

__device__ __forceinline__ float gelu_exact(float x) {
  return 0.5f * x * (1.f + erff(x * 0.7071067811865475f));
}
__device__ __forceinline__ unsigned short f2bf(float f) {  // RNE
  unsigned u = __float_as_uint(f);
  return (unsigned short)((u + 0x7FFF + ((u >> 16) & 1)) >> 16);
}
__device__ __forceinline__ float bf2f(unsigned short s) {
  return __uint_as_float(((unsigned)s) << 16);
}
__device__ __forceinline__ float blo(unsigned w) {
  return __uint_as_float(w << 16);
}
__device__ __forceinline__ float bhi(unsigned w) {
  return __uint_as_float(w & 0xFFFF0000u);
}

__device__ __forceinline__ int btype(int bx, int nb0, int nb01) {
  return bx < nb0 ? 0 : (bx < nb01 ? 1 : 2);
}

// ---------------- swizzled BK=64 MFMA GEMM body ----------------
template <int KSTEPS, bool A_FP32>
__device__ __forceinline__ void gemm_body(
    const void* __restrict__ Av, int lda, const unsigned short* __restrict__ BT,
    int ldb, f32x4* acc, int M, int bm) {
  __shared__ unsigned short As[64 * 64];
  __shared__ unsigned short Bs[128 * 64];
  const int tid = threadIdx.x;
  const int wv = tid >> 6, l = tid & 63;
  for (int ks = 0; ks < KSTEPS; ks++) {
    const int kk = ks * 64;
    #pragma unroll
    for (int p = 0; p < 2; p++) {
      int idx = tid + p * 256;
      int r = idx >> 3, c = idx & 7;
      int gr = bm + r;
      unsigned short tmp[8] = {0, 0, 0, 0, 0, 0, 0, 0};
      if (gr < M) {
        if (A_FP32) {
          const float* src = (const float*)Av + (size_t)gr * lda + kk + c * 8;
          float4 f0 = *(const float4*)src;
          float4 f1 = *(const float4*)(src + 4);
          tmp[0] = f2bf(f0.x); tmp[1] = f2bf(f0.y);
          tmp[2] = f2bf(f0.z); tmp[3] = f2bf(f0.w);
          tmp[4] = f2bf(f1.x); tmp[5] = f2bf(f1.y);
          tmp[6] = f2bf(f1.z); tmp[7] = f2bf(f1.w);
        } else {
          *(uint4*)tmp = *(const uint4*)((const unsigned short*)Av +
                                         (size_t)gr * lda + kk + c * 8);
        }
      }
      *(uint4*)&As[r * 64 + ((c ^ (r & 7)) * 8)] = *(const uint4*)tmp;
    }
    #pragma unroll
    for (int p = 0; p < 4; p++) {
      int idx = tid + p * 256;
      int r = idx >> 3, c = idx & 7;
      uint4 v = *(const uint4*)(BT + (size_t)r * ldb + kk + c * 8);
      *(uint4*)&Bs[r * 64 + ((c ^ (r & 7)) * 8)] = v;
    }
    __syncthreads();
    const int arow = wv * 16 + (l & 15);
    #pragma unroll
    for (int ksub = 0; ksub < 2; ksub++) {
      int ch = ksub * 4 + (l >> 4);
      short8v af = *(const short8v*)&As[arow * 64 + ((ch ^ (arow & 7)) * 8)];
      #pragma unroll
      for (int n = 0; n < 8; n++) {
        int brow = n * 16 + (l & 15);
        short8v bf =
            *(const short8v*)&Bs[brow * 64 + ((ch ^ (brow & 7)) * 8)];
        acc[n] =
            __builtin_amdgcn_mfma_f32_16x16x32_bf16(af, bf, acc[n], 0, 0, 0);
      }
    }
    __syncthreads();
  }
}

// ---------------- weight prep: bf16 transposed copies ----------------
__global__ __launch_bounds__(256) void prep_weights(
    const float* __restrict__ W_in, const float* __restrict__ W_kqv,
    const float* __restrict__ W_o, unsigned short* __restrict__ WinT,
    unsigned short* __restrict__ Wk0T, unsigned short* __restrict__ WoT) {
  int idx = blockIdx.x * 256 + threadIdx.x;
  const int N1 = 3 * 128 * 64, N2 = 2 * 384 * 128, N3 = 6 * 128 * 128;
  if (idx < N1) {
    int t = idx / 8192, rem = idx - t * 8192;
    int n = rem >> 6, k = rem & 63;
    WinT[idx] = f2bf(W_in[(size_t)t * 64 * 128 + (size_t)k * 128 + n]);
  } else if (idx < N1 + N2) {
    int r = idx - N1;
    int lyr = r / (384 * 128), rem = r - lyr * (384 * 128);
    int n = rem >> 7, k = rem & 127;
    Wk0T[r] = f2bf(W_kqv[(size_t)lyr * 3 * 128 * 384 + (size_t)k * 384 + n]);
  } else if (idx < N1 + N2 + N3) {
    int r = idx - N1 - N2;
    int lt = r / (128 * 128), rem = r - lt * (128 * 128);
    int n = rem >> 7, k = rem & 127;
    WoT[r] = f2bf(W_o[(size_t)lt * 128 * 128 + (size_t)k * 128 + n]);
  }
}

// ---------------- weight folding (BOTH layers; y = layer) ----------------
__global__ __launch_bounds__(256) void fold_weights2(
    const float* __restrict__ W_kqv, const float* __restrict__ b_kqv,
    const float* __restrict__ a_rel, const float* __restrict__ m_rel,
    unsigned short* __restrict__ WeT, float* __restrict__ be) {
  const int lyr = blockIdx.y;
  const size_t DD = (size_t)H * D * D;
  const float* Wl = W_kqv + (size_t)lyr * 3 * HID * LDK;
  const float* bl = b_kqv + (size_t)lyr * 3 * LDK;
  const float* Al = a_rel + (size_t)lyr * 4 * DD;
  const float* Ml = m_rel + (size_t)lyr * 4 * DD;
  unsigned short* WeTl = WeT + (size_t)lyr * 2 * 384 * 128;
  float* bel = be + (size_t)lyr * 2 * 384;
  int idx = blockIdx.x * 256 + threadIdx.x;
  const int NW_ = 2 * 128 * 384;
  if (idx < NW_) {
    int tt = idx / (128 * 384);
    int rem = idx - tt * (128 * 384);
    int r = rem / 384, c = rem - r * 384;
    int slice = c >> 7, h = (c >> 5) & 3, j = c & 31;
    const float* Wsrc = Wl + (size_t)(tt + 1) * 128 * 384 + (size_t)r * 384;
    float acc = 0.f;
    if (slice == 0) {
      const float* A = Al + ((size_t)tt * H + h) * D * D;
      for (int d = 0; d < 32; d++) acc += Wsrc[h * 32 + d] * A[d * 32 + j];
    } else if (slice == 1) {
      const float* A = Al + ((size_t)(2 + tt) * H + h) * D * D;
      for (int e = 0; e < 32; e++)
        acc += Wsrc[128 + h * 32 + e] * A[j * 32 + e];
    } else {
      const float* Mm = Ml + ((size_t)tt * H + h) * D * D;
      for (int d = 0; d < 32; d++)
        acc += Wsrc[256 + h * 32 + d] * Mm[d * 32 + j];
    }
    WeTl[(size_t)tt * 384 * 128 + (size_t)c * 128 + r] = f2bf(acc);
  } else if (idx < NW_ + 2 * 384) {
    int rem = idx - NW_;
    int tt = rem / 384, c = rem - tt * 384;
    int slice = c >> 7, h = (c >> 5) & 3, j = c & 31;
    const float* bsrc = bl + (size_t)(tt + 1) * 384;
    float acc = 0.f;
    if (slice == 0) {
      const float* A = Al + ((size_t)tt * H + h) * D * D;
      for (int d = 0; d < 32; d++) acc += bsrc[h * 32 + d] * A[d * 32 + j];
    } else if (slice == 1) {
      const float* A = Al + ((size_t)(2 + tt) * H + h) * D * D;
      for (int e = 0; e < 32; e++)
        acc += bsrc[128 + h * 32 + e] * A[j * 32 + e];
    } else {
      const float* Mm = Ml + ((size_t)tt * H + h) * D * D;
      for (int d = 0; d < 32; d++)
        acc += bsrc[256 + h * 32 + d] * Mm[d * 32 + j];
    }
    bel[rem] = acc;
  }
}

// input proj: xs = relu(x @ W_in[t] + b_in[t])
__global__ __launch_bounds__(256) void in_fused(
    const float* __restrict__ xa, const float* __restrict__ xw,
    const float* __restrict__ xo, const unsigned short* __restrict__ WinT,
    const float* __restrict__ b_in, unsigned short* __restrict__ xs, int nb0,
    int nb01) {
  int t = btype(blockIdx.x, nb0, nb01);
  int base = t == 0 ? 0 : (t == 1 ? nb0 : nb01);
  int M = t == 0 ? NA : (t == 1 ? NW : NO);
  int off = t == 0 ? 0 : (t == 1 ? NA : NA + NW);
  const float* A = t == 0 ? xa : (t == 1 ? xw : xo);
  const int bm = (blockIdx.x - base) * 64;
  f32x4 acc[8] = {};
  gemm_body<1, true>(A, 64, WinT + (size_t)t * 128 * 64, 64, acc, M, bm);
  const int l = threadIdx.x & 63, wv = threadIdx.x >> 6;
  const float* bias = b_in + t * HID;
  unsigned short* C = xs + (size_t)off * HID;
  #pragma unroll
  for (int n = 0; n < 8; n++) {
    int col = n * 16 + (l & 15);
    float bb = bias[col];
    #pragma unroll
    for (int j = 0; j < 4; j++) {
      int row = bm + wv * 16 + (l >> 4) * 4 + j;
      if (row < M) C[(size_t)row * HID + col] = f2bf(fmaxf(acc[n][j] + bb, 0.f));
    }
  }
}

// kqv proj: full-width 64x384 per block; A staged once (full K in LDS),
// 3 internal 128-col tiles. t=0 raw Wk0T; t=1,2 folded WeT.
__global__ __launch_bounds__(256) void kqv_fused(
    const unsigned short* __restrict__ xs, const unsigned short* __restrict__ Wk0Tl,
    const float* __restrict__ b0, const unsigned short* __restrict__ WeT,
    const float* __restrict__ be, unsigned short* __restrict__ kqvB, int nb0,
    int nb01) {
  __shared__ unsigned short As[64 * 128];   // 16 KB, full K
  __shared__ unsigned short Bs[128 * 128];  // 32 KB per col-tile
  int t = btype(blockIdx.x, nb0, nb01);
  int base = t == 0 ? 0 : (t == 1 ? nb0 : nb01);
  int M = t == 0 ? NA : (t == 1 ? NW : NO);
  int off = t == 0 ? 0 : (t == 1 ? NA : NA + NW);
  const unsigned short* BT =
      (t == 0 ? Wk0Tl : WeT + (size_t)(t - 1) * 384 * 128);
  const float* bias = t == 0 ? b0 : be + (size_t)(t - 1) * 384;
  const int bm = (blockIdx.x - base) * 64;
  const int tid = threadIdx.x;
  const int wv = tid >> 6, l = tid & 63;
  // stage A once: 64 rows x 16 chunks (16B), XOR-16 swizzle; GLOBAL rows.
  #pragma unroll
  for (int p = 0; p < 4; p++) {
    int idx = tid + p * 256;
    int r = idx >> 4, c = idx & 15;
    int gr = bm + r;
    uint4 v = {0, 0, 0, 0};
    if (gr < M)
      v = *(const uint4*)(xs + (size_t)(off + gr) * HID + c * 8);
    *(uint4*)&As[r * 128 + ((c ^ (r & 15)) * 8)] = v;
  }
  const int arow = wv * 16 + (l & 15);
  unsigned short* C = kqvB + (size_t)off * LDK;
  for (int bn = 0; bn < 384; bn += 128) {
    if (bn) __syncthreads();  // protect Bs before restage
    #pragma unroll
    for (int p = 0; p < 8; p++) {
      int idx = tid + p * 256;
      int r = idx >> 4, c = idx & 15;
      uint4 v = *(const uint4*)(BT + (size_t)(bn + r) * 128 + c * 8);
      *(uint4*)&Bs[r * 128 + ((c ^ (r & 15)) * 8)] = v;
    }
    __syncthreads();
    f32x4 acc[8] = {};
    #pragma unroll
    for (int ks = 0; ks < 4; ks++) {
      int ch = ks * 4 + (l >> 4);
      short8v af = *(const short8v*)&As[arow * 128 + ((ch ^ (arow & 15)) * 8)];
      #pragma unroll
      for (int n = 0; n < 8; n++) {
        int brow = n * 16 + (l & 15);
        short8v bf =
            *(const short8v*)&Bs[brow * 128 + ((ch ^ (brow & 15)) * 8)];
        acc[n] =
            __builtin_amdgcn_mfma_f32_16x16x32_bf16(af, bf, acc[n], 0, 0, 0);
      }
    }
    #pragma unroll
    for (int n = 0; n < 8; n++) {
      int col = bn + n * 16 + (l & 15);
      float bb = bias[col];
      #pragma unroll
      for (int j = 0; j < 4; j++) {
        int row = bm + wv * 16 + (l >> 4) * 4 + j;
        if (row < M) C[(size_t)row * LDK + col] = f2bf(acc[n][j] + bb);
      }
    }
  }
}

// fused: xs = relu(LN( g*(agg_gelu @ W_o + b_o) + (1-g)*xs ))
// + (doHead && t==0): out[row] = base + b_head + xs_row . w_head
__global__ __launch_bounds__(256) void wo_ln_fused(
    const unsigned short* __restrict__ kqvB, const unsigned short* __restrict__ WoTl,
    const float* __restrict__ bl, unsigned short* __restrict__ xs,
    const float* __restrict__ skipl, const float* __restrict__ gll,
    const float* __restrict__ bll, int nb0, int nb01, int doHead,
    const float* __restrict__ w_head, const float* __restrict__ b_head,
    const float* __restrict__ basep, float* __restrict__ outHead) {
  int t = btype(blockIdx.x, nb0, nb01);
  int base = t == 0 ? 0 : (t == 1 ? nb0 : nb01);
  int M = t == 0 ? NA : (t == 1 ? NW : NO);
  int off = t == 0 ? 0 : (t == 1 ? NA : NA + NW);
  const int bm = (blockIdx.x - base) * 64;
  f32x4 acc[8] = {};
  gemm_body<2, false>(kqvB + (size_t)off * LDK + HID, LDK,
                      WoTl + (size_t)t * 128 * 128, 128, acc, M, bm);
  const int l = threadIdx.x & 63, wv = threadIdx.x >> 6;
  const float* bias = bl + t * HID;
  const float* gln = gll + t * HID;
  const float* bln = bll + t * HID;
  unsigned short* xsT = xs + (size_t)off * HID;
  const float g = 1.f / (1.f + expf(-skipl[t]));
  const bool hd = (doHead != 0) && (t == 0);
  float bb[8], gl8[8], bl8[8], wh8[8];
  #pragma unroll
  for (int n = 0; n < 8; n++) {
    int col = n * 16 + (l & 15);
    bb[n] = bias[col];
    gl8[n] = gln[col];
    bl8[n] = bln[col];
    wh8[n] = hd ? w_head[col] : 0.f;
  }
  #pragma unroll
  for (int j = 0; j < 4; j++) {
    int row = bm + wv * 16 + (l >> 4) * 4 + j;
    bool ok = row < M;
    float vv[8], sum = 0.f, sq = 0.f;
    #pragma unroll
    for (int n = 0; n < 8; n++) {
      int col = n * 16 + (l & 15);
      float xo = ok ? bf2f(xsT[(size_t)row * HID + col]) : 0.f;
      float val = g * (acc[n][j] + bb[n]) + (1.f - g) * xo;
      vv[n] = val;
      sum += val;
      sq += val * val;
    }
    #pragma unroll
    for (int m = 1; m < 16; m <<= 1) {
      sum += __shfl_xor(sum, m, 64);
      sq += __shfl_xor(sq, m, 64);
    }
    float mu = sum * (1.f / 128.f);
    float var = sq * (1.f / 128.f) - mu * mu;
    float r = rsqrtf(var + 1e-5f);
    if (ok) {
      float dot = 0.f;
      #pragma unroll
      for (int n = 0; n < 8; n++) {
        float y = fmaxf((vv[n] - mu) * r * gl8[n] + bl8[n], 0.f);
        xsT[(size_t)row * HID + n * 16 + (l & 15)] = f2bf(y);
        dot += bf2f(f2bf(y)) * wh8[n];  // use bf16-rounded y (matches old path)
      }
      if (hd) {
        dot += __shfl_xor(dot, 1, 64);
        dot += __shfl_xor(dot, 2, 64);
        dot += __shfl_xor(dot, 4, 64);
        dot += __shfl_xor(dot, 8, 64);
        if ((l & 15) == 0) outHead[row] = basep[0] + b_head[0] + dot;
      }
    }
  }
}

// ---------------- CSR build (deterministic, 4 ets fused) ----------------
__global__ __launch_bounds__(256) void csr_hist4(
    const int* __restrict__ d0, const int* __restrict__ d1,
    const int* __restrict__ d2, const int* __restrict__ d3,
    int* __restrict__ cnt) {
  int t = blockIdx.x * 256 + threadIdx.x;
  if (t >= 4 * E) return;
  int et = t / E, e = t - et * E;
  const int* dp = et == 0 ? d0 : et == 1 ? d1 : et == 2 ? d2 : d3;
  int base = et == 0 ? 0 : et == 1 ? NA : et == 2 ? 2 * NA : 2 * NA + NW;
  atomicAdd(&cnt[base + dp[e]], 1);
}

// fused per-256-block scan over all 4 et regions (grid partitioned by et)
__global__ __launch_bounds__(256) void scan_block_all(
    const int* __restrict__ cnt, int* __restrict__ rpAll,
    int* __restrict__ bsum) {
  const int nbA = (NA + 255) / 256, nbW = (NW + 255) / 256,
            nbO = (NO + 255) / 256;
  int bx = blockIdx.x;
  int et, bbase, cbase, rpo, n;
  if (bx < nbA) { et = 0; bbase = 0; cbase = 0; rpo = 0; n = NA; }
  else if (bx < 2 * nbA) { et = 1; bbase = nbA; cbase = NA; rpo = NA + 1; n = NA; }
  else if (bx < 2 * nbA + nbW) {
    et = 2; bbase = 2 * nbA; cbase = 2 * NA; rpo = 2 * (NA + 1); n = NW;
  } else {
    et = 3; bbase = 2 * nbA + nbW; cbase = 2 * NA + NW;
    rpo = 2 * (NA + 1) + (NW + 1); n = NO;
  }
  int lb = bx - bbase;
  __shared__ int tmp[256];
  int i = lb * 256 + threadIdx.x;
  int v = (i < n) ? cnt[cbase + i] : 0;
  tmp[threadIdx.x] = v;
  __syncthreads();
  int acc = v;
  for (int off = 1; off < 256; off <<= 1) {
    int other = (threadIdx.x >= off) ? tmp[threadIdx.x - off] : 0;
    __syncthreads();
    acc += other;
    tmp[threadIdx.x] = acc;
    __syncthreads();
  }
  if (i < n) rpAll[rpo + i] = acc - v;
  if (threadIdx.x == 255) bsum[et * 512 + lb] = acc;
}

// fused bsum scans: 4 blocks, one per et
__global__ __launch_bounds__(256) void scan_bsums_all(int* __restrict__ bsum) {
  int et = blockIdx.x;
  int nb = et < 2 ? (NA + 255) / 256 : (et == 2 ? (NW + 255) / 256
                                                : (NO + 255) / 256);
  int* bs = bsum + et * 512;
  __shared__ int tmp[256];
  __shared__ int carry;
  if (threadIdx.x == 0) carry = 0;
  __syncthreads();
  for (int start = 0; start < nb; start += 256) {
    int i = start + threadIdx.x;
    int v = (i < nb) ? bs[i] : 0;
    tmp[threadIdx.x] = v;
    __syncthreads();
    int acc = v;
    for (int off = 1; off < 256; off <<= 1) {
      int other = (threadIdx.x >= off) ? tmp[threadIdx.x - off] : 0;
      __syncthreads();
      acc += other;
      tmp[threadIdx.x] = acc;
      __syncthreads();
    }
    int c = carry;
    if (i < nb) bs[i] = c + acc - v;
    __syncthreads();
    if (threadIdx.x == 255) carry = c + acc;
    __syncthreads();
  }
}

__device__ __forceinline__ void et_of_node(int i, int& et, int& base, int& nd,
                                           int& rpo) {
  if (i < NA) { et = 0; base = 0; nd = NA; rpo = 0; }
  else if (i < 2 * NA) { et = 1; base = NA; nd = NA; rpo = NA + 1; }
  else if (i < 2 * NA + NW) { et = 2; base = 2 * NA; nd = NW; rpo = 2 * (NA + 1); }
  else { et = 3; base = 2 * NA + NW; nd = NO; rpo = 2 * (NA + 1) + NW + 1; }
}

__global__ __launch_bounds__(256) void csr_finalize4(
    int* __restrict__ rpAll, const int* __restrict__ bsum,
    int* __restrict__ cursor) {
  int i = blockIdx.x * 256 + threadIdx.x;
  if (i >= 2 * NA + NW + NO) return;
  int et, base, nd, rpo;
  et_of_node(i, et, base, nd, rpo);
  int local = i - base;
  int v = rpAll[rpo + local] + bsum[et * 512 + (local >> 8)];
  rpAll[rpo + local] = v;
  cursor[base + local] = v;
  if (local == 0) rpAll[rpo + nd] = E;
}

__global__ __launch_bounds__(256) void csr_scatter4(
    const int* __restrict__ d0, const int* __restrict__ d1,
    const int* __restrict__ d2, const int* __restrict__ d3,
    int* __restrict__ cursor, int* __restrict__ ceAll) {
  int t = blockIdx.x * 256 + threadIdx.x;
  if (t >= 4 * E) return;
  int et = t / E, e = t - et * E;
  const int* dp = et == 0 ? d0 : et == 1 ? d1 : et == 2 ? d2 : d3;
  int base = et == 0 ? 0 : et == 1 ? NA : et == 2 ? 2 * NA : 2 * NA + NW;
  int slot = atomicAdd(&cursor[base + dp[e]], 1);
  ceAll[(size_t)et * E + slot] = e;
}

// merged: per (et, dst) sort its CSR range + emit srcOf run + desc halves
__global__ __launch_bounds__(256) void csr_finish(
    const int* __restrict__ rpAll, int* __restrict__ ceAll,
    const int* __restrict__ s0, const int* __restrict__ s1,
    const int* __restrict__ s2, const int* __restrict__ s3,
    int* __restrict__ srcOf, int* __restrict__ descI) {
  int i = blockIdx.x * 256 + threadIdx.x;
  if (i >= 2 * NA + NW + NO) return;
  int et, base, nd, rpo;
  et_of_node(i, et, base, nd, rpo);
  int local = i - base;
  int b = rpAll[rpo + local], e = rpAll[rpo + local + 1];
  int* ce = ceAll + (size_t)et * E;
  // canonical order (ascending edge index) -> deterministic fp sums
  for (int k = b + 1; k < e; k++) {
    int key = ce[k];
    int j = k - 1;
    while (j >= b && ce[j] > key) { ce[j + 1] = ce[j]; j--; }
    ce[j + 1] = key;
  }
  // slot-ordered GLOBAL src ids for this dst's run
  const int* sp = et == 0 ? s0 : et == 1 ? s1 : et == 2 ? s2 : s3;
  int sOff = et == 0 ? NA : et == 1 ? NA + NW : 0;
  int* so = srcOf + (size_t)et * E;
  for (int k = b; k < e; k++) so[k] = sOff + sp[ce[k]];
  // packed desc halves (A dsts: et0 writes x,y; et1 writes z,w)
  if (et == 0) {
    descI[(size_t)local * 4 + 0] = b;
    descI[(size_t)local * 4 + 1] = e;
  } else if (et == 1) {
    descI[(size_t)local * 4 + 2] = b;
    descI[(size_t)local * 4 + 3] = e;
  } else {
    int dl = (et == 2) ? NA + local : NA + NW + local;
    descI[(size_t)dl * 4 + 0] = b;
    descI[(size_t)dl * 4 + 1] = e;
    descI[(size_t)dl * 4 + 2] = 0;
    descI[(size_t)dl * 4 + 3] = 0;
  }
}

// ---------------- fused attention (online softmax, 2-wide pipelined) ------
__global__ __launch_bounds__(256) void attn_fused(
    const unsigned short* __restrict__ kqv, const int4* __restrict__ desc,
    const int* __restrict__ srcOf, const float* __restrict__ Pl,
    const float* __restrict__ Ml, unsigned short* __restrict__ out) {
  int dl = (blockIdx.x * 256 + threadIdx.x) >> 6;
  int lane = threadIdx.x & 63;
  if (dl >= NTOT) return;
  int q = lane >> 4, p = lane & 15;
  int4 dd = desc[dl];
  int b0 = dd.x, e0 = dd.y, b1 = dd.z, e1 = dd.w;
  int et23 = -1;
  const int* so0;
  const int* so1 = srcOf;
  float ps0, ps1 = 0.f;
  if (dl < NA) {
    so0 = srcOf; so1 = srcOf + E;
    ps0 = Pl[q] * SCALE; ps1 = Pl[H + q] * SCALE;
  } else if (dl < NA + NW) {
    so0 = srcOf + 2 * (size_t)E;
    ps0 = Pl[2 * H + q] * SCALE;
    et23 = 2;
  } else {
    so0 = srcOf + 3 * (size_t)E;
    ps0 = Pl[3 * H + q] * SCALE;
    et23 = 3;
  }
  const int n0 = e0 - b0;
  const int n01 = n0 + (e1 - b1);
  auto srcAt = [&](int t) -> int {
    return (t < n0) ? so0[b0 + t] : so1[b1 + (t - n0)];
  };
  unsigned qv = *(const unsigned*)(kqv + (size_t)dl * LDK + HID + lane * 2);
  float qx = blo(qv), qy = bhi(qv);
  const int lo2 = lane * 2;

  float m = -INFINITY, den = 0.f, ax = 0.f, ay = 0.f;
  unsigned ka = 0, va = 0, kb = 0, vb = 0;
  int i2 = 0, i3 = 0;
  if (n01 > 0) {
    const unsigned short* r = kqv + (size_t)srcAt(0) * LDK;
    ka = *(const unsigned*)(r + lo2);
    va = *(const unsigned*)(r + 2 * HID + lo2);
  }
  if (n01 > 1) {
    const unsigned short* r = kqv + (size_t)srcAt(1) * LDK;
    kb = *(const unsigned*)(r + lo2);
    vb = *(const unsigned*)(r + 2 * HID + lo2);
  }
  if (n01 > 2) i2 = srcAt(2);
  if (n01 > 3) i3 = srcAt(3);
  int t = 0;
  for (; t + 1 < n01; t += 2) {
    unsigned pka = ka, pva = va, pkb = kb, pvb = vb;
    float psa = (t < n0) ? ps0 : ps1;
    float psb = (t + 1 < n0) ? ps0 : ps1;
    if (t + 2 < n01) {
      const unsigned short* r = kqv + (size_t)i2 * LDK;
      ka = *(const unsigned*)(r + lo2);
      va = *(const unsigned*)(r + 2 * HID + lo2);
    }
    if (t + 3 < n01) {
      const unsigned short* r = kqv + (size_t)i3 * LDK;
      kb = *(const unsigned*)(r + lo2);
      vb = *(const unsigned*)(r + 2 * HID + lo2);
    }
    if (t + 4 < n01) i2 = srcAt(t + 4);
    if (t + 5 < n01) i3 = srcAt(t + 5);
    float sa = qx * blo(pka) + qy * bhi(pka);
    float sb = qx * blo(pkb) + qy * bhi(pkb);
    sa += __shfl_xor(sa, 1, 64);
    sb += __shfl_xor(sb, 1, 64);
    sa += __shfl_xor(sa, 2, 64);
    sb += __shfl_xor(sb, 2, 64);
    sa += __shfl_xor(sa, 4, 64);
    sb += __shfl_xor(sb, 4, 64);
    sa += __shfl_xor(sa, 8, 64);
    sb += __shfl_xor(sb, 8, 64);
    sa *= psa;
    sb *= psb;
    float nm = fmaxf(m, fmaxf(sa, sb));
    float c = __expf(m - nm);
    float wa = __expf(sa - nm), wb = __expf(sb - nm);
    den = den * c + wa + wb;
    ax = ax * c + wa * blo(pva) + wb * blo(pvb);
    ay = ay * c + wa * bhi(pva) + wb * bhi(pvb);
    m = nm;
  }
  if (t < n01) {
    float ps = (t < n0) ? ps0 : ps1;
    float s = qx * blo(ka) + qy * bhi(ka);
    s += __shfl_xor(s, 1, 64);
    s += __shfl_xor(s, 2, 64);
    s += __shfl_xor(s, 4, 64);
    s += __shfl_xor(s, 8, 64);
    s *= ps;
    float nm = fmaxf(m, s);
    float c = __expf(m - nm);
    float w = __expf(s - nm);
    den = den * c + w;
    ax = ax * c + w * blo(va);
    ay = ay * c + w * bhi(va);
  }
  float inv = 1.f / (den + 1e-16f);
  ax *= inv;
  ay *= inv;
  if (et23 >= 0) {
    const float* Mm = Ml + ((size_t)et23 * H + q) * D * D;
    int base = lane & 48;
    float o0 = 0.f, o1 = 0.f;
    #pragma unroll
    for (int j = 0; j < 16; j++) {
      float s0 = __shfl(ax, base + j, 64);
      float s1 = __shfl(ay, base + j, 64);
      float2 m0 = *(const float2*)&Mm[(2 * j) * 32 + 2 * p];
      float2 m1 = *(const float2*)&Mm[(2 * j + 1) * 32 + 2 * p];
      o0 += s0 * m0.x + s1 * m1.x;
      o1 += s0 * m0.y + s1 * m1.y;
    }
    ax = o0; ay = o1;
  }
  unsigned ov = (unsigned)f2bf(gelu_exact(ax)) |
                ((unsigned)f2bf(gelu_exact(ay)) << 16);
  *(unsigned*)(out + (size_t)dl * LDK + HID + lane * 2) = ov;
}

}  // namespace

extern "C" void kernel_launch(void* const* d_in, const int* in_sizes, int n_in,
                              void* d_out, int out_size, void* d_ws,
                              size_t ws_size, hipStream_t stream) {
  const float* x_a = (const float*)d_in[0];
  const float* x_w = (const float*)d_in[1];
  const float* x_o = (const float*)d_in[2];
  const float* W_in = (const float*)d_in[3];
  const float* b_in = (const float*)d_in[4];
  const float* W_kqv = (const float*)d_in[5];
  const float* b_kqv = (const float*)d_in[6];
  const float* a_rel = (const float*)d_in[7];
  const float* m_rel = (const float*)d_in[8];
  const float* p_rel = (const float*)d_in[9];
  const float* skip_p = (const float*)d_in[10];
  const float* W_o = (const float*)d_in[11];
  const float* b_o = (const float*)d_in[12];
  const float* ln_g = (const float*)d_in[13];
  const float* ln_b = (const float*)d_in[14];
  const float* w_head = (const float*)d_in[15];
  const float* b_head = (const float*)d_in[16];
  const float* basep = (const float*)d_in[17];
  const int* srcs[4] = {(const int*)d_in[18], (const int*)d_in[20],
                        (const int*)d_in[22], (const int*)d_in[24]};
  const int* dsts[4] = {(const int*)d_in[19], (const int*)d_in[21],
                        (const int*)d_in[23], (const int*)d_in[25]};

  // ---- workspace layout (~186 MB) ----
  const size_t SZ_XS = (size_t)NTOT * HID * 2;
  const size_t SZ_KQV = (size_t)NTOT * LDK * 2;
  const size_t SZ_WINT = (size_t)3 * 128 * 64 * 2;
  const size_t SZ_WK0T = (size_t)2 * 384 * 128 * 2;
  const size_t SZ_WOT = (size_t)6 * 128 * 128 * 2;
  const size_t SZ_WET = (size_t)2 * 2 * 384 * 128 * 2;  // both layers
  const size_t SZ_BE = ((size_t)2 * 2 * 384 * 4 + 63) & ~63ull;
  const size_t SZ_SD = (size_t)4 * E * 4;
  const size_t SZ_DESC = (size_t)NTOT * 16;
  const int CNT_TOT = 2 * NA + NW + NO;
  const int RP_TOT = 2 * (NA + 1) + (NW + 1) + (NO + 1);
  const size_t SZ_RP = ((size_t)RP_TOT * 4 + 63) & ~63ull;
  const size_t SZ_CE = (size_t)4 * E * 4;
  const size_t SZ_CU = ((size_t)CNT_TOT * 4 + 63) & ~63ull;
  const size_t SZ_BS = 4 * 512 * 4;
  const size_t need = SZ_XS + SZ_KQV + SZ_WINT + SZ_WK0T + SZ_WOT + SZ_WET +
                      SZ_BE + SZ_SD + SZ_DESC + SZ_RP + SZ_CE + 2 * SZ_CU +
                      SZ_BS;
  if (ws_size < need) return;

  char* p = (char*)d_ws;
  unsigned short* xs = (unsigned short*)p;    p += SZ_XS;
  unsigned short* kqvB = (unsigned short*)p;  p += SZ_KQV;
  unsigned short* WinT = (unsigned short*)p;  p += SZ_WINT;
  unsigned short* Wk0T = (unsigned short*)p;  p += SZ_WK0T;
  unsigned short* WoT = (unsigned short*)p;   p += SZ_WOT;
  unsigned short* WeT = (unsigned short*)p;   p += SZ_WET;
  float* beB = (float*)p;                     p += SZ_BE;
  int* srcOf = (int*)p;                       p += SZ_SD;
  int4* descB = (int4*)p;                     p += SZ_DESC;
  int* rpAll = (int*)p;                       p += SZ_RP;
  int* ceAll = (int*)p;                       p += SZ_CE;
  int* cursor = (int*)p;                      p += SZ_CU;
  int* cnt = (int*)p;                         p += SZ_CU;
  int* bsum = (int*)p;

  const int CNTT = 2 * NA + NW + NO;
  const int e4b = (4 * E + 255) / 256;
  const int nb0 = (NA + 63) / 64, nb01 = nb0 + (NW + 63) / 64;
  const int nbTot = nb01 + (NO + 63) / 64;
  const int nbA = (NA + 255) / 256, nbW = (NW + 255) / 256,
            nbO = (NO + 255) / 256;

  // ---- CSR build (once) ----
  hipMemsetAsync(cnt, 0, (size_t)CNTT * 4, stream);
  csr_hist4<<<e4b, 256, 0, stream>>>(dsts[0], dsts[1], dsts[2], dsts[3], cnt);
  scan_block_all<<<2 * nbA + nbW + nbO, 256, 0, stream>>>(cnt, rpAll, bsum);
  scan_bsums_all<<<4, 256, 0, stream>>>(bsum);
  csr_finalize4<<<(CNTT + 255) / 256, 256, 0, stream>>>(rpAll, bsum, cursor);
  csr_scatter4<<<e4b, 256, 0, stream>>>(dsts[0], dsts[1], dsts[2], dsts[3],
                                        cursor, ceAll);
  csr_finish<<<(CNTT + 255) / 256, 256, 0, stream>>>(
      rpAll, ceAll, srcs[0], srcs[1], srcs[2], srcs[3], srcOf, (int*)descB);

  // ---- weight prep (incl. both-layer folds) + input projection ----
  prep_weights<<<(3 * 128 * 64 + 2 * 384 * 128 + 6 * 128 * 128 + 255) / 256,
                 256, 0, stream>>>(W_in, W_kqv, W_o, WinT, Wk0T, WoT);
  fold_weights2<<<dim3((2 * 128 * 384 + 2 * 384 + 255) / 256, 2), 256, 0,
                  stream>>>(W_kqv, b_kqv, a_rel, m_rel, WeT, beB);
  in_fused<<<nbTot, 256, 0, stream>>>(x_a, x_w, x_o, WinT, b_in, xs, nb0, nb01);

  const size_t DD = (size_t)H * D * D;
  for (int l = 0; l < 2; l++) {
    const float* Ml = m_rel + (size_t)l * 4 * DD;
    const float* Pl = p_rel + (size_t)l * 4 * H;
    const float* bl = b_kqv + (size_t)l * 3 * LDK;
    kqv_fused<<<nbTot, 256, 0, stream>>>(
        xs, Wk0T + (size_t)l * 384 * 128, bl,
        WeT + (size_t)l * 2 * 384 * 128, beB + (size_t)l * 2 * 384, kqvB, nb0,
        nb01);
    attn_fused<<<(NTOT + 3) / 4, 256, 0, stream>>>(kqvB, descB, srcOf, Pl, Ml,
                                                   kqvB);
    wo_ln_fused<<<nbTot, 256, 0, stream>>>(
        kqvB, WoT + (size_t)l * 3 * 128 * 128, b_o + (size_t)l * 3 * HID, xs,
        skip_p + l * 3, ln_g + (size_t)l * 3 * HID, ln_b + (size_t)l * 3 * HID,
        nb0, nb01, (l == 1) ? 1 : 0, w_head, b_head, basep, (float*)d_out);
  }
}